// Round 1
// baseline (1799.626 us; speedup 1.0000x reference)
//
#include <hip/hip_runtime.h>
#include <hip/hip_bf16.h>

using bf16 = __hip_bfloat16;

constexpr int B = 8, C = 64, H = 256, W = 256;
constexpr int HWs = H * W;               // 65536
constexpr int NPIX = B * H * W;          // 524288
constexpr long long NELEM = (long long)B * C * H * W;  // 33554432
constexpr int CS = 32;
constexpr int Hd = 128, Wd = 128;
constexpr int HWd = Hd * Wd;             // 16384
constexpr int NDOWN = B * CS * HWd;      // 4194304
constexpr float EPS = 1e-6f;
constexpr float SCALE = 0.17677669529663687f;  // 32^-0.5

__device__ __forceinline__ float b2f(bf16 v) { return __bfloat162float(v); }
__device__ __forceinline__ bf16 f2b(float v) { return __float2bfloat16(v); }

// ---- K1: channel LayerNorm over C (biased var), x0 f32 -> x bf16 ----
__global__ __launch_bounds__(256) void ln_kernel(
    const float* __restrict__ x0, const float* __restrict__ lw,
    const float* __restrict__ lb, bf16* __restrict__ xo) {
  int p = blockIdx.x * 256 + threadIdx.x;
  int b = p >> 16, hw = p & (HWs - 1);
  const float* xp = x0 + (size_t)b * C * HWs + hw;
  float xv[C];
  float s = 0.f;
#pragma unroll
  for (int c = 0; c < C; ++c) { xv[c] = xp[(size_t)c * HWs]; s += xv[c]; }
  float mu = s * (1.f / C);
  float vs = 0.f;
#pragma unroll
  for (int c = 0; c < C; ++c) { float d = xv[c] - mu; vs += d * d; }
  float rstd = rsqrtf(vs * (1.f / C) + EPS);
  bf16* yp = xo + (size_t)b * C * HWs + hw;
#pragma unroll
  for (int c = 0; c < C; ++c)
    yp[(size_t)c * HWs] = f2b(lw[c] * ((xv[c] - mu) * rstd) + lb[c]);
}

// ---- K2: depthwise 3x3 (zero pad) + bias -> x1 bf16; block-reduced pool sums ----
__global__ __launch_bounds__(256) void dw_kernel(
    const bf16* __restrict__ x, const float* __restrict__ dww,
    const float* __restrict__ dwb, bf16* __restrict__ x1,
    float* __restrict__ pool) {
  int w = threadIdx.x;
  int h = blockIdx.x, c = blockIdx.y, b = blockIdx.z;
  const bf16* xp = x + ((size_t)b * C + c) * HWs;
  float kk[9];
#pragma unroll
  for (int i = 0; i < 9; ++i) kk[i] = dww[c * 9 + i];
  float acc = dwb[c];
#pragma unroll
  for (int di = 0; di < 3; ++di) {
    int hh = h + di - 1;
    if (hh < 0 || hh >= H) continue;
#pragma unroll
    for (int dj = 0; dj < 3; ++dj) {
      int ww = w + dj - 1;
      if (ww < 0 || ww >= W) continue;
      acc += kk[di * 3 + dj] * b2f(xp[hh * W + ww]);
    }
  }
  x1[((size_t)b * C + c) * HWs + h * W + w] = f2b(acc);
  // block reduction -> one atomic per block
  float v = acc;
#pragma unroll
  for (int off = 32; off > 0; off >>= 1) v += __shfl_down(v, off, 64);
  __shared__ float red[4];
  int lane = threadIdx.x & 63, wid = threadIdx.x >> 6;
  if (lane == 0) red[wid] = v;
  __syncthreads();
  if (threadIdx.x == 0)
    atomicAdd(&pool[b * C + c], red[0] + red[1] + red[2] + red[3]);
}

// ---- K3: ECA channel attention from pooled means -> ca[b][c] (sigmoid) ----
__global__ __launch_bounds__(512) void eca_kernel(
    const float* __restrict__ pool, const float* __restrict__ w1,
    const float* __restrict__ w2, const float* __restrict__ w3,
    const float* __restrict__ wc, float* __restrict__ ca) {
  int tid = threadIdx.x;          // 0..511
  int b = tid >> 6, c = tid & 63;
  __shared__ float m[8][64], t1[8][64], t2[8][64], t3[8][64];
  m[b][c] = pool[tid] * (1.f / HWs);
  __syncthreads();
  auto gm = [&](int cc) -> float { return (cc >= 0 && cc < 64) ? m[b][cc] : 0.f; };
  t1[b][c] = w1[0] * gm(c - 1) + w1[1] * gm(c) + w1[2] * gm(c + 1);
  t2[b][c] = w2[0] * gm(c - 2) + w2[1] * gm(c) + w2[2] * gm(c + 2);
  t3[b][c] = w3[0] * gm(c - 4) + w3[1] * gm(c) + w3[2] * gm(c + 4);
  __syncthreads();
  auto g1 = [&](int cc) -> float { return (cc >= 0 && cc < 64) ? t1[b][cc] : 0.f; };
  auto g2 = [&](int cc) -> float { return (cc >= 0 && cc < 64) ? t2[b][cc] : 0.f; };
  auto g3 = [&](int cc) -> float { return (cc >= 0 && cc < 64) ? t3[b][cc] : 0.f; };
  float z = 0.f;
#pragma unroll
  for (int k = 0; k < 3; ++k) {
    z += wc[0 * 3 + k] * g1(c + k - 1);
    z += wc[1 * 3 + k] * g2(c + k - 1);
    z += wc[2 * 3 + k] * g3(c + k - 1);
  }
  ca[tid] = 1.f / (1.f + __expf(-z));
}

// ---- K4: q/k/v 1x1 projections (weights via scalar loads), v *= ca ----
__global__ __launch_bounds__(256) void qkv_kernel(
    const bf16* __restrict__ x, const float* __restrict__ wq,
    const float* __restrict__ wk, const float* __restrict__ wv,
    const float* __restrict__ ca, bf16* __restrict__ q,
    bf16* __restrict__ k, bf16* __restrict__ v) {
  int p = blockIdx.x * 256 + threadIdx.x;
  int b = p >> 16, hw = p & (HWs - 1);
  const bf16* xp = x + (size_t)b * C * HWs + hw;
  float xv[C];
#pragma unroll
  for (int c = 0; c < C; ++c) xv[c] = b2f(xp[(size_t)c * HWs]);
  size_t base = (size_t)b * C * HWs + hw;
  for (int o = 0; o < C; ++o) {
    float aq = 0.f, ak = 0.f, av = 0.f;
#pragma unroll
    for (int c = 0; c < C; ++c) {
      float xc = xv[c];
      aq = fmaf(wq[o * C + c], xc, aq);
      ak = fmaf(wk[o * C + c], xc, ak);
      av = fmaf(wv[o * C + c], xc, av);
    }
    av *= ca[b * C + o];
    q[base + (size_t)o * HWs] = f2b(aq);
    k[base + (size_t)o * HWs] = f2b(ak);
    v[base + (size_t)o * HWs] = f2b(av);
  }
}

// ---- K5: depthwise 2x2 stride-2 downsample of k/v channels 32..63 ----
__global__ __launch_bounds__(256) void down_kernel(
    const bf16* __restrict__ k, const bf16* __restrict__ v,
    const float* __restrict__ dw, const float* __restrict__ db,
    bf16* __restrict__ kd, bf16* __restrict__ vd) {
  int idx = blockIdx.x * 256 + threadIdx.x;
  if (idx >= NDOWN) return;
  int j = idx & (Wd - 1);
  int i = (idx >> 7) & (Hd - 1);
  int c = (idx >> 14) & 31;
  int b = idx >> 19;
  const bf16* kp = k + ((size_t)b * C + 32 + c) * HWs;
  const bf16* vp = v + ((size_t)b * C + 32 + c) * HWs;
  float w00 = dw[c * 4 + 0], w01 = dw[c * 4 + 1];
  float w10 = dw[c * 4 + 2], w11 = dw[c * 4 + 3];
  int r0 = 2 * i, c0 = 2 * j;
  float ka = w00 * b2f(kp[r0 * W + c0]) + w01 * b2f(kp[r0 * W + c0 + 1]) +
             w10 * b2f(kp[(r0 + 1) * W + c0]) + w11 * b2f(kp[(r0 + 1) * W + c0 + 1]) + db[c];
  float va = w00 * b2f(vp[r0 * W + c0]) + w01 * b2f(vp[r0 * W + c0 + 1]) +
             w10 * b2f(vp[(r0 + 1) * W + c0]) + w11 * b2f(vp[(r0 + 1) * W + c0 + 1]) + db[c];
  kd[idx] = f2b(ka);
  vd[idx] = f2b(va);
}

// ---- K6: branch 0 window attention (ws=8, shift -4, channels 0..31) ----
__global__ void attn0_kernel(const bf16* __restrict__ q,
                             const bf16* __restrict__ k,
                             const bf16* __restrict__ v,
                             bf16* __restrict__ y) {
  int widx = blockIdx.x;
  int b = widx >> 10, wy = (widx >> 5) & 31, wx = widx & 31;
  int t = threadIdx.x;                 // token 0..63
  int ty = t >> 3, tx = t & 7;
  int r = (wy * 8 + ty + 4) & 255;     // rolled -> orig coords
  int cc = (wx * 8 + tx + 4) & 255;
  __shared__ float ks_[64][32];
  __shared__ float vs_[64][32];
  size_t base = (size_t)b * C * HWs + r * W + cc;
  float qv[32];
#pragma unroll
  for (int c = 0; c < 32; ++c) {
    qv[c] = b2f(q[base + (size_t)c * HWs]);
    ks_[t][c] = b2f(k[base + (size_t)c * HWs]);
    vs_[t][c] = b2f(v[base + (size_t)c * HWs]);
  }
  __syncthreads();
  float s[64];
  float mx = -1e30f;
#pragma unroll
  for (int j = 0; j < 64; ++j) {
    float acc = 0.f;
#pragma unroll
    for (int c = 0; c < 32; ++c) acc += qv[c] * ks_[j][c];
    acc *= SCALE;
    s[j] = acc;
    mx = fmaxf(mx, acc);
  }
  float sum = 0.f;
#pragma unroll
  for (int j = 0; j < 64; ++j) { s[j] = __expf(s[j] - mx); sum += s[j]; }
  float inv = 1.f / sum;
  float yv[32];
#pragma unroll
  for (int c = 0; c < 32; ++c) yv[c] = 0.f;
#pragma unroll
  for (int j = 0; j < 64; ++j) {
    float pj = s[j] * inv;
#pragma unroll
    for (int c = 0; c < 32; ++c) yv[c] += pj * vs_[j][c];
  }
#pragma unroll
  for (int c = 0; c < 32; ++c) y[base + (size_t)c * HWs] = f2b(yv[c]);
}

// ---- K7: branch 1 (q ws=8 shift -4 ch 32..63; k/v downsampled, shift -2, ws=4) ----
__global__ void attn1_kernel(const bf16* __restrict__ q,
                             const bf16* __restrict__ kd,
                             const bf16* __restrict__ vd,
                             bf16* __restrict__ y) {
  int widx = blockIdx.x;
  int b = widx >> 10, wy = (widx >> 5) & 31, wx = widx & 31;
  int t = threadIdx.x;
  int ty = t >> 3, tx = t & 7;
  int r = (wy * 8 + ty + 4) & 255;
  int cc = (wx * 8 + tx + 4) & 255;
  __shared__ float ks_[16][32];
  __shared__ float vs_[16][32];
  for (int i = t; i < 16 * 32; i += 64) {
    int j = i >> 5, c = i & 31;
    int jy = j >> 2, jx = j & 3;
    int rr = (wy * 4 + jy + 2) & 127;
    int cd = (wx * 4 + jx + 2) & 127;
    size_t kb = ((size_t)b * CS + c) * HWd + rr * Wd + cd;
    ks_[j][c] = b2f(kd[kb]);
    vs_[j][c] = b2f(vd[kb]);
  }
  size_t base = ((size_t)b * C + 32) * HWs + r * W + cc;
  float qv[32];
#pragma unroll
  for (int c = 0; c < 32; ++c) qv[c] = b2f(q[base + (size_t)c * HWs]);
  __syncthreads();
  float s[16];
  float mx = -1e30f;
#pragma unroll
  for (int j = 0; j < 16; ++j) {
    float acc = 0.f;
#pragma unroll
    for (int c = 0; c < 32; ++c) acc += qv[c] * ks_[j][c];
    acc *= SCALE;
    s[j] = acc;
    mx = fmaxf(mx, acc);
  }
  float sum = 0.f;
#pragma unroll
  for (int j = 0; j < 16; ++j) { s[j] = __expf(s[j] - mx); sum += s[j]; }
  float inv = 1.f / sum;
  float yv[32];
#pragma unroll
  for (int c = 0; c < 32; ++c) yv[c] = 0.f;
#pragma unroll
  for (int j = 0; j < 16; ++j) {
    float pj = s[j] * inv;
#pragma unroll
    for (int c = 0; c < 32; ++c) yv[c] += pj * vs_[j][c];
  }
#pragma unroll
  for (int c = 0; c < 32; ++c) y[base + (size_t)c * HWs] = f2b(yv[c]);
}

// ---- K8: spatial gate + output projection + residual ----
__global__ __launch_bounds__(256) void final_kernel(
    const bf16* __restrict__ y, const bf16* __restrict__ x1,
    const float* __restrict__ x0, const float* __restrict__ sa_w,
    const float* __restrict__ sa_b, const float* __restrict__ po_w,
    const float* __restrict__ po_b, float* __restrict__ out) {
  int p = blockIdx.x * 256 + threadIdx.x;
  int b = p >> 16, hw = p & (HWs - 1);
  size_t base = (size_t)b * C * HWs + hw;
  float yv[C];
#pragma unroll
  for (int c = 0; c < C; ++c) yv[c] = b2f(y[base + (size_t)c * HWs]);
  float sdot = sa_b[0];
#pragma unroll
  for (int c = 0; c < C; ++c) sdot = fmaf(sa_w[c], yv[c], sdot);
  float sg = 1.f / (1.f + __expf(-sdot));
#pragma unroll
  for (int c = 0; c < C; ++c) yv[c] += sg * b2f(x1[base + (size_t)c * HWs]);
  for (int o = 0; o < C; ++o) {
    float acc = po_b[o];
#pragma unroll
    for (int c = 0; c < C; ++c) acc = fmaf(po_w[o * C + c], yv[c], acc);
    out[base + (size_t)o * HWs] = acc + x0[base + (size_t)o * HWs];
  }
}

extern "C" void kernel_launch(void* const* d_in, const int* in_sizes, int n_in,
                              void* d_out, int out_size, void* d_ws, size_t ws_size,
                              hipStream_t stream) {
  const float* x0    = (const float*)d_in[0];
  const float* ln_w  = (const float*)d_in[1];
  const float* ln_b  = (const float*)d_in[2];
  const float* dw_w  = (const float*)d_in[3];
  const float* dw_b  = (const float*)d_in[4];
  const float* ew1   = (const float*)d_in[5];
  const float* ew2   = (const float*)d_in[6];
  const float* ew3   = (const float*)d_in[7];
  const float* ewc   = (const float*)d_in[8];
  const float* wq    = (const float*)d_in[9];
  const float* wk    = (const float*)d_in[10];
  const float* wv    = (const float*)d_in[11];
  const float* dwn_w = (const float*)d_in[12];
  const float* dwn_b = (const float*)d_in[13];
  const float* sa_w  = (const float*)d_in[14];
  const float* sa_b  = (const float*)d_in[15];
  const float* po_w  = (const float*)d_in[16];
  const float* po_b  = (const float*)d_in[17];
  float* out = (float*)d_out;

  char* ws = (char*)d_ws;
  const size_t NB = (size_t)NELEM * sizeof(bf16);     // 67,108,864
  const size_t NDB = (size_t)NDOWN * sizeof(bf16);    // 8,388,608
  bf16* xbuf  = (bf16*)(ws);                 // also reused as ybuf after qkv
  bf16* x1buf = (bf16*)(ws + NB);
  bf16* qbuf  = (bf16*)(ws + 2 * NB);
  bf16* kbuf  = (bf16*)(ws + 3 * NB);
  bf16* vbuf  = (bf16*)(ws + 4 * NB);
  bf16* kdbuf = (bf16*)(ws + 5 * NB);
  bf16* vdbuf = (bf16*)(ws + 5 * NB + NDB);
  float* pool = (float*)(ws + 5 * NB + 2 * NDB);
  float* cabuf = pool + B * C;
  bf16* ybuf = xbuf;  // x dead after qkv_kernel; reuse for attention output

  hipMemsetAsync(pool, 0, B * C * sizeof(float), stream);
  ln_kernel<<<NPIX / 256, 256, 0, stream>>>(x0, ln_w, ln_b, xbuf);
  dw_kernel<<<dim3(H, C, B), 256, 0, stream>>>(xbuf, dw_w, dw_b, x1buf, pool);
  eca_kernel<<<1, 512, 0, stream>>>(pool, ew1, ew2, ew3, ewc, cabuf);
  qkv_kernel<<<NPIX / 256, 256, 0, stream>>>(xbuf, wq, wk, wv, cabuf, qbuf, kbuf, vbuf);
  down_kernel<<<NDOWN / 256, 256, 0, stream>>>(kbuf, vbuf, dwn_w, dwn_b, kdbuf, vdbuf);
  attn0_kernel<<<B * 32 * 32, 64, 0, stream>>>(qbuf, kbuf, vbuf, ybuf);
  attn1_kernel<<<B * 32 * 32, 64, 0, stream>>>(qbuf, kdbuf, vdbuf, ybuf);
  final_kernel<<<NPIX / 256, 256, 0, stream>>>(ybuf, x1buf, x0, sa_w, sa_b, po_w, po_b, out);
}

// Round 2
// 1065.096 us; speedup vs baseline: 1.6896x; 1.6896x over previous
//
#include <hip/hip_runtime.h>
#include <hip/hip_bf16.h>

using bf16 = __hip_bfloat16;

constexpr int B = 8, C = 64, H = 256, W = 256;
constexpr int HWs = H * W;               // 65536
constexpr int NPIX = B * H * W;          // 524288
constexpr long long NELEM = (long long)B * C * H * W;  // 33554432
constexpr int CS = 32;
constexpr int Hd = 128, Wd = 128;
constexpr int HWd = Hd * Wd;             // 16384
constexpr int NDOWN = B * CS * HWd;      // 4194304
constexpr float EPS = 1e-6f;
constexpr float SCALE = 0.17677669529663687f;  // 32^-0.5

typedef __attribute__((ext_vector_type(8))) short short8v;     // 8 bf16 (4 VGPRs)
typedef __attribute__((ext_vector_type(8))) unsigned short ushort8v;
typedef __attribute__((ext_vector_type(4))) float f32x4;

__device__ __forceinline__ float b2f(bf16 v) { return __bfloat162float(v); }
__device__ __forceinline__ bf16 f2b(float v) { return __float2bfloat16(v); }
__device__ __forceinline__ unsigned short f2bu(float v) {
  bf16 t = __float2bfloat16(v);
  unsigned short u;
  __builtin_memcpy(&u, &t, 2);
  return u;
}
__device__ __forceinline__ float bu2f(unsigned short u) {
  bf16 t;
  __builtin_memcpy(&t, &u, 2);
  return __bfloat162float(t);
}

// ---- K1: channel LayerNorm over C (biased var), x0 f32 -> x bf16 ----
__global__ __launch_bounds__(256) void ln_kernel(
    const float* __restrict__ x0, const float* __restrict__ lw,
    const float* __restrict__ lb, bf16* __restrict__ xo) {
  int p = blockIdx.x * 256 + threadIdx.x;
  int b = p >> 16, hw = p & (HWs - 1);
  const float* xp = x0 + (size_t)b * C * HWs + hw;
  float xv[C];
  float s = 0.f;
#pragma unroll
  for (int c = 0; c < C; ++c) { xv[c] = xp[(size_t)c * HWs]; s += xv[c]; }
  float mu = s * (1.f / C);
  float vs = 0.f;
#pragma unroll
  for (int c = 0; c < C; ++c) { float d = xv[c] - mu; vs += d * d; }
  float rstd = rsqrtf(vs * (1.f / C) + EPS);
  bf16* yp = xo + (size_t)b * C * HWs + hw;
#pragma unroll
  for (int c = 0; c < C; ++c)
    yp[(size_t)c * HWs] = f2b(lw[c] * ((xv[c] - mu) * rstd) + lb[c]);
}

// ---- K2: depthwise 3x3 (zero pad) + bias -> x1 bf16; block-reduced pool sums ----
__global__ __launch_bounds__(256) void dw_kernel(
    const bf16* __restrict__ x, const float* __restrict__ dww,
    const float* __restrict__ dwb, bf16* __restrict__ x1,
    float* __restrict__ pool) {
  int w = threadIdx.x;
  int h = blockIdx.x, c = blockIdx.y, b = blockIdx.z;
  const bf16* xp = x + ((size_t)b * C + c) * HWs;
  float kk[9];
#pragma unroll
  for (int i = 0; i < 9; ++i) kk[i] = dww[c * 9 + i];
  float acc = dwb[c];
#pragma unroll
  for (int di = 0; di < 3; ++di) {
    int hh = h + di - 1;
    if (hh < 0 || hh >= H) continue;
#pragma unroll
    for (int dj = 0; dj < 3; ++dj) {
      int ww = w + dj - 1;
      if (ww < 0 || ww >= W) continue;
      acc += kk[di * 3 + dj] * b2f(xp[hh * W + ww]);
    }
  }
  x1[((size_t)b * C + c) * HWs + h * W + w] = f2b(acc);
  float v = acc;
#pragma unroll
  for (int off = 32; off > 0; off >>= 1) v += __shfl_down(v, off, 64);
  __shared__ float red[4];
  int lane = threadIdx.x & 63, wid = threadIdx.x >> 6;
  if (lane == 0) red[wid] = v;
  __syncthreads();
  if (threadIdx.x == 0)
    atomicAdd(&pool[b * C + c], red[0] + red[1] + red[2] + red[3]);
}

// ---- K3: ECA channel attention from pooled means -> ca[b][c] (sigmoid) ----
__global__ __launch_bounds__(512) void eca_kernel(
    const float* __restrict__ pool, const float* __restrict__ w1,
    const float* __restrict__ w2, const float* __restrict__ w3,
    const float* __restrict__ wc, float* __restrict__ ca) {
  int tid = threadIdx.x;          // 0..511
  int b = tid >> 6, c = tid & 63;
  __shared__ float m[8][64], t1[8][64], t2[8][64], t3[8][64];
  m[b][c] = pool[tid] * (1.f / HWs);
  __syncthreads();
  auto gm = [&](int cc) -> float { return (cc >= 0 && cc < 64) ? m[b][cc] : 0.f; };
  t1[b][c] = w1[0] * gm(c - 1) + w1[1] * gm(c) + w1[2] * gm(c + 1);
  t2[b][c] = w2[0] * gm(c - 2) + w2[1] * gm(c) + w2[2] * gm(c + 2);
  t3[b][c] = w3[0] * gm(c - 4) + w3[1] * gm(c) + w3[2] * gm(c + 4);
  __syncthreads();
  auto g1 = [&](int cc) -> float { return (cc >= 0 && cc < 64) ? t1[b][cc] : 0.f; };
  auto g2 = [&](int cc) -> float { return (cc >= 0 && cc < 64) ? t2[b][cc] : 0.f; };
  auto g3 = [&](int cc) -> float { return (cc >= 0 && cc < 64) ? t3[b][cc] : 0.f; };
  float z = 0.f;
#pragma unroll
  for (int k = 0; k < 3; ++k) {
    z += wc[0 * 3 + k] * g1(c + k - 1);
    z += wc[1 * 3 + k] * g2(c + k - 1);
    z += wc[2 * 3 + k] * g3(c + k - 1);
  }
  ca[tid] = 1.f / (1.f + __expf(-z));
}

// ---- K4: q/k/v 1x1 projections via MFMA. GEMM [64xK64] x [K64 x NPIX].
// A/B fragments both use k-slot map k = 4*(lane>>4) + (j&3) + 16*(j>>2)
// (any bijection works if applied to BOTH operands). C/D: col=lane&15,
// row=(lane>>4)*4+reg (HW-verified). ----
__global__ __launch_bounds__(256) void qkv_mfma_kernel(
    const unsigned short* __restrict__ x, const float* __restrict__ wq,
    const float* __restrict__ wk, const float* __restrict__ wv,
    const float* __restrict__ ca, unsigned short* __restrict__ q,
    unsigned short* __restrict__ k, unsigned short* __restrict__ v) {
  int lane = threadIdx.x & 63, wid = threadIdx.x >> 6;
  int lr = lane & 15, lg = lane >> 4;
  // Preload weight fragments (persist across tile loop).
  short8v aq[4][2], ak[4][2], av[4][2];
#pragma unroll
  for (int mt = 0; mt < 4; ++mt)
#pragma unroll
    for (int ks = 0; ks < 2; ++ks) {
      int rowoff = (mt * 16 + lr) * 64 + ks * 32 + lg * 4;
      short8v tq, tk, tv;
#pragma unroll
      for (int j = 0; j < 8; ++j) {
        int kj = (j & 3) + 16 * (j >> 2);
        tq[j] = (short)f2bu(wq[rowoff + kj]);
        tk[j] = (short)f2bu(wk[rowoff + kj]);
        tv[j] = (short)f2bu(wv[rowoff + kj]);
      }
      aq[mt][ks] = tq; ak[mt][ks] = tk; av[mt][ks] = tv;
    }
  const int NT = NPIX / 16;  // 32768 tiles of 16 pixels
  for (int t = blockIdx.x * 4 + wid; t < NT; t += gridDim.x * 4) {
    int p0 = t * 16;
    int b = p0 >> 16;
    int hw = (p0 & (HWs - 1)) + lr;
    const unsigned short* xp = x + (size_t)b * C * HWs + hw;
    short8v bx[2];
#pragma unroll
    for (int ks = 0; ks < 2; ++ks) {
      short8v tt;
#pragma unroll
      for (int j = 0; j < 8; ++j) {
        int c = ks * 32 + lg * 4 + (j & 3) + 16 * (j >> 2);
        tt[j] = (short)xp[(size_t)c * HWs];
      }
      bx[ks] = tt;
    }
    f32x4 zero = {0.f, 0.f, 0.f, 0.f};
    f32x4 acq[4], ack[4], acv[4];
#pragma unroll
    for (int mt = 0; mt < 4; ++mt) {
      acq[mt] = __builtin_amdgcn_mfma_f32_16x16x32_bf16(aq[mt][0], bx[0], zero, 0, 0, 0);
      acq[mt] = __builtin_amdgcn_mfma_f32_16x16x32_bf16(aq[mt][1], bx[1], acq[mt], 0, 0, 0);
      ack[mt] = __builtin_amdgcn_mfma_f32_16x16x32_bf16(ak[mt][0], bx[0], zero, 0, 0, 0);
      ack[mt] = __builtin_amdgcn_mfma_f32_16x16x32_bf16(ak[mt][1], bx[1], ack[mt], 0, 0, 0);
      acv[mt] = __builtin_amdgcn_mfma_f32_16x16x32_bf16(av[mt][0], bx[0], zero, 0, 0, 0);
      acv[mt] = __builtin_amdgcn_mfma_f32_16x16x32_bf16(av[mt][1], bx[1], acv[mt], 0, 0, 0);
    }
    size_t obase = (size_t)b * C * HWs + hw;
    const float* cab = ca + b * 64;
#pragma unroll
    for (int mt = 0; mt < 4; ++mt)
#pragma unroll
      for (int i = 0; i < 4; ++i) {
        int o = mt * 16 + lg * 4 + i;
        size_t off = obase + (size_t)o * HWs;
        q[off] = f2bu(acq[mt][i]);
        k[off] = f2bu(ack[mt][i]);
        v[off] = f2bu(acv[mt][i] * cab[o]);
      }
  }
}

// ---- K5: depthwise 2x2 stride-2 downsample of k/v channels 32..63 ----
__global__ __launch_bounds__(256) void down_kernel(
    const bf16* __restrict__ k, const bf16* __restrict__ v,
    const float* __restrict__ dw, const float* __restrict__ db,
    bf16* __restrict__ kd, bf16* __restrict__ vd) {
  int idx = blockIdx.x * 256 + threadIdx.x;
  if (idx >= NDOWN) return;
  int j = idx & (Wd - 1);
  int i = (idx >> 7) & (Hd - 1);
  int c = (idx >> 14) & 31;
  int b = idx >> 19;
  const bf16* kp = k + ((size_t)b * C + 32 + c) * HWs;
  const bf16* vp = v + ((size_t)b * C + 32 + c) * HWs;
  float w00 = dw[c * 4 + 0], w01 = dw[c * 4 + 1];
  float w10 = dw[c * 4 + 2], w11 = dw[c * 4 + 3];
  int r0 = 2 * i, c0 = 2 * j;
  float ka = w00 * b2f(kp[r0 * W + c0]) + w01 * b2f(kp[r0 * W + c0 + 1]) +
             w10 * b2f(kp[(r0 + 1) * W + c0]) + w11 * b2f(kp[(r0 + 1) * W + c0 + 1]) + db[c];
  float va = w00 * b2f(vp[r0 * W + c0]) + w01 * b2f(vp[r0 * W + c0 + 1]) +
             w10 * b2f(vp[(r0 + 1) * W + c0]) + w11 * b2f(vp[(r0 + 1) * W + c0 + 1]) + db[c];
  kd[idx] = f2b(ka);
  vd[idx] = f2b(va);
}

// ---- K6: branch 0 window attention (ws=8, shift -4, channels 0..31) ----
__global__ void attn0_kernel(const bf16* __restrict__ q,
                             const bf16* __restrict__ k,
                             const bf16* __restrict__ v,
                             bf16* __restrict__ y) {
  int widx = blockIdx.x;
  int b = widx >> 10, wy = (widx >> 5) & 31, wx = widx & 31;
  int t = threadIdx.x;                 // token 0..63
  int ty = t >> 3, tx = t & 7;
  int r = (wy * 8 + ty + 4) & 255;     // rolled -> orig coords
  int cc = (wx * 8 + tx + 4) & 255;
  __shared__ float ks_[64][32];
  __shared__ float vs_[64][32];
  size_t base = (size_t)b * C * HWs + r * W + cc;
  float qv[32];
#pragma unroll
  for (int c = 0; c < 32; ++c) {
    qv[c] = b2f(q[base + (size_t)c * HWs]);
    ks_[t][c] = b2f(k[base + (size_t)c * HWs]);
    vs_[t][c] = b2f(v[base + (size_t)c * HWs]);
  }
  __syncthreads();
  float s[64];
  float mx = -1e30f;
#pragma unroll
  for (int j = 0; j < 64; ++j) {
    float acc = 0.f;
#pragma unroll
    for (int c = 0; c < 32; ++c) acc += qv[c] * ks_[j][c];
    acc *= SCALE;
    s[j] = acc;
    mx = fmaxf(mx, acc);
  }
  float sum = 0.f;
#pragma unroll
  for (int j = 0; j < 64; ++j) { s[j] = __expf(s[j] - mx); sum += s[j]; }
  float inv = 1.f / sum;
  float yv[32];
#pragma unroll
  for (int c = 0; c < 32; ++c) yv[c] = 0.f;
#pragma unroll
  for (int j = 0; j < 64; ++j) {
    float pj = s[j] * inv;
#pragma unroll
    for (int c = 0; c < 32; ++c) yv[c] += pj * vs_[j][c];
  }
#pragma unroll
  for (int c = 0; c < 32; ++c) y[base + (size_t)c * HWs] = f2b(yv[c]);
}

// ---- K7: branch 1 (q ws=8 shift -4 ch 32..63; k/v downsampled, shift -2, ws=4) ----
__global__ void attn1_kernel(const bf16* __restrict__ q,
                             const bf16* __restrict__ kd,
                             const bf16* __restrict__ vd,
                             bf16* __restrict__ y) {
  int widx = blockIdx.x;
  int b = widx >> 10, wy = (widx >> 5) & 31, wx = widx & 31;
  int t = threadIdx.x;
  int ty = t >> 3, tx = t & 7;
  int r = (wy * 8 + ty + 4) & 255;
  int cc = (wx * 8 + tx + 4) & 255;
  __shared__ float ks_[16][32];
  __shared__ float vs_[16][32];
  for (int i = t; i < 16 * 32; i += 64) {
    int j = i >> 5, c = i & 31;
    int jy = j >> 2, jx = j & 3;
    int rr = (wy * 4 + jy + 2) & 127;
    int cd = (wx * 4 + jx + 2) & 127;
    size_t kb = ((size_t)b * CS + c) * HWd + rr * Wd + cd;
    ks_[j][c] = b2f(kd[kb]);
    vs_[j][c] = b2f(vd[kb]);
  }
  size_t base = ((size_t)b * C + 32) * HWs + r * W + cc;
  float qv[32];
#pragma unroll
  for (int c = 0; c < 32; ++c) qv[c] = b2f(q[base + (size_t)c * HWs]);
  __syncthreads();
  float s[16];
  float mx = -1e30f;
#pragma unroll
  for (int j = 0; j < 16; ++j) {
    float acc = 0.f;
#pragma unroll
    for (int c = 0; c < 32; ++c) acc += qv[c] * ks_[j][c];
    acc *= SCALE;
    s[j] = acc;
    mx = fmaxf(mx, acc);
  }
  float sum = 0.f;
#pragma unroll
  for (int j = 0; j < 16; ++j) { s[j] = __expf(s[j] - mx); sum += s[j]; }
  float inv = 1.f / sum;
  float yv[32];
#pragma unroll
  for (int c = 0; c < 32; ++c) yv[c] = 0.f;
#pragma unroll
  for (int j = 0; j < 16; ++j) {
    float pj = s[j] * inv;
#pragma unroll
    for (int c = 0; c < 32; ++c) yv[c] += pj * vs_[j][c];
  }
#pragma unroll
  for (int c = 0; c < 32; ++c) y[base + (size_t)c * HWs] = f2b(yv[c]);
}

// ---- K8: fused spatial gate + output projection (MFMA) + residual.
// Block = 256 threads = 4 waves, 64 pixels. y tile staged in LDS,
// per-pixel gate via cooperative reduction, z = y + sg*x1 in LDS,
// then per-wave MFMA over a 16-pixel subtile. ----
__global__ __launch_bounds__(256) void final_mfma_kernel(
    const unsigned short* __restrict__ y, const unsigned short* __restrict__ x1,
    const float* __restrict__ x0, const float* __restrict__ sa_w,
    const float* __restrict__ sa_b, const float* __restrict__ po_w,
    const float* __restrict__ po_b, float* __restrict__ out) {
  __shared__ unsigned short zs[64][72];   // 144B rows: 16B-aligned, 2-way-free MFMA reads
  __shared__ float part[4][64];
  __shared__ float sgs[64];
  int tid = threadIdx.x;
  int lane = tid & 63, wid = tid >> 6;
  int lr = lane & 15, lg = lane >> 4;
  // Preload po_w fragments.
  short8v ap[4][2];
#pragma unroll
  for (int mt = 0; mt < 4; ++mt)
#pragma unroll
    for (int ks = 0; ks < 2; ++ks) {
      int rowoff = (mt * 16 + lr) * 64 + ks * 32 + lg * 4;
      short8v tt;
#pragma unroll
      for (int j = 0; j < 8; ++j) {
        int kj = (j & 3) + 16 * (j >> 2);
        tt[j] = (short)f2bu(po_w[rowoff + kj]);
      }
      ap[mt][ks] = tt;
    }
  int cc = tid >> 2, qx = (tid & 3) * 16;   // staging: channel cc, pixel range [qx,qx+16)
  const int NBLK = NPIX / 64;               // 8192
  for (int blk = blockIdx.x; blk < NBLK; blk += gridDim.x) {
    int p0 = blk * 64;
    int b = p0 >> 16, hw0 = p0 & (HWs - 1);
    size_t rbase = (size_t)b * C * HWs + (size_t)cc * HWs + hw0 + qx;
    ushort8v y0 = *(const ushort8v*)(y + rbase);
    ushort8v y1 = *(const ushort8v*)(y + rbase + 8);
    ushort8v a0 = *(const ushort8v*)(x1 + rbase);
    ushort8v a1 = *(const ushort8v*)(x1 + rbase + 8);
    *(ushort8v*)&zs[cc][qx] = y0;
    *(ushort8v*)&zs[cc][qx + 8] = y1;
    __syncthreads();
    {  // partial gate dot: thread -> pixel (tid&63), channel quarter (tid>>6)
      int p = tid & 63, qr = tid >> 6;
      float s = 0.f;
#pragma unroll
      for (int c2 = 0; c2 < 16; ++c2)
        s += sa_w[qr * 16 + c2] * bu2f(zs[qr * 16 + c2][p]);
      part[qr][p] = s;
    }
    __syncthreads();
    if (tid < 64) {
      float sd = part[0][tid] + part[1][tid] + part[2][tid] + part[3][tid] + sa_b[0];
      sgs[tid] = 1.f / (1.f + __expf(-sd));
    }
    __syncthreads();
    {  // z = y + sg*x1 (in-place on own staged elements)
      ushort8v z0, z1;
#pragma unroll
      for (int i = 0; i < 8; ++i) {
        z0[i] = f2bu(bu2f(y0[i]) + sgs[qx + i] * bu2f(a0[i]));
        z1[i] = f2bu(bu2f(y1[i]) + sgs[qx + 8 + i] * bu2f(a1[i]));
      }
      *(ushort8v*)&zs[cc][qx] = z0;
      *(ushort8v*)&zs[cc][qx + 8] = z1;
    }
    __syncthreads();
    // MFMA: B fragment from LDS columns, same k-slot map as A.
    short8v bz[2];
#pragma unroll
    for (int ks = 0; ks < 2; ++ks) {
      short8v tt;
#pragma unroll
      for (int j = 0; j < 8; ++j) {
        int c2 = ks * 32 + lg * 4 + (j & 3) + 16 * (j >> 2);
        tt[j] = (short)zs[c2][wid * 16 + lr];
      }
      bz[ks] = tt;
    }
    f32x4 zero = {0.f, 0.f, 0.f, 0.f};
    f32x4 acc[4];
#pragma unroll
    for (int mt = 0; mt < 4; ++mt) {
      acc[mt] = __builtin_amdgcn_mfma_f32_16x16x32_bf16(ap[mt][0], bz[0], zero, 0, 0, 0);
      acc[mt] = __builtin_amdgcn_mfma_f32_16x16x32_bf16(ap[mt][1], bz[1], acc[mt], 0, 0, 0);
    }
    size_t pbase = (size_t)b * C * HWs + hw0 + wid * 16 + lr;
#pragma unroll
    for (int mt = 0; mt < 4; ++mt)
#pragma unroll
      for (int i = 0; i < 4; ++i) {
        int o = mt * 16 + lg * 4 + i;
        out[pbase + (size_t)o * HWs] = acc[mt][i] + po_b[o] + x0[pbase + (size_t)o * HWs];
      }
    __syncthreads();  // zs reused next iteration
  }
}

extern "C" void kernel_launch(void* const* d_in, const int* in_sizes, int n_in,
                              void* d_out, int out_size, void* d_ws, size_t ws_size,
                              hipStream_t stream) {
  const float* x0    = (const float*)d_in[0];
  const float* ln_w  = (const float*)d_in[1];
  const float* ln_b  = (const float*)d_in[2];
  const float* dw_w  = (const float*)d_in[3];
  const float* dw_b  = (const float*)d_in[4];
  const float* ew1   = (const float*)d_in[5];
  const float* ew2   = (const float*)d_in[6];
  const float* ew3   = (const float*)d_in[7];
  const float* ewc   = (const float*)d_in[8];
  const float* wq    = (const float*)d_in[9];
  const float* wk    = (const float*)d_in[10];
  const float* wv    = (const float*)d_in[11];
  const float* dwn_w = (const float*)d_in[12];
  const float* dwn_b = (const float*)d_in[13];
  const float* sa_w  = (const float*)d_in[14];
  const float* sa_b  = (const float*)d_in[15];
  const float* po_w  = (const float*)d_in[16];
  const float* po_b  = (const float*)d_in[17];
  float* out = (float*)d_out;

  char* ws = (char*)d_ws;
  const size_t NB = (size_t)NELEM * sizeof(bf16);     // 67,108,864
  const size_t NDB = (size_t)NDOWN * sizeof(bf16);    // 8,388,608
  bf16* xbuf  = (bf16*)(ws);                 // also reused as ybuf after qkv
  bf16* x1buf = (bf16*)(ws + NB);
  bf16* qbuf  = (bf16*)(ws + 2 * NB);
  bf16* kbuf  = (bf16*)(ws + 3 * NB);
  bf16* vbuf  = (bf16*)(ws + 4 * NB);
  bf16* kdbuf = (bf16*)(ws + 5 * NB);
  bf16* vdbuf = (bf16*)(ws + 5 * NB + NDB);
  float* pool = (float*)(ws + 5 * NB + 2 * NDB);
  float* cabuf = pool + B * C;
  bf16* ybuf = xbuf;  // x dead after qkv; reuse for attention output

  hipMemsetAsync(pool, 0, B * C * sizeof(float), stream);
  ln_kernel<<<NPIX / 256, 256, 0, stream>>>(x0, ln_w, ln_b, xbuf);
  dw_kernel<<<dim3(H, C, B), 256, 0, stream>>>(xbuf, dw_w, dw_b, x1buf, pool);
  eca_kernel<<<1, 512, 0, stream>>>(pool, ew1, ew2, ew3, ewc, cabuf);
  qkv_mfma_kernel<<<2048, 256, 0, stream>>>((const unsigned short*)xbuf, wq, wk, wv,
                                            cabuf, (unsigned short*)qbuf,
                                            (unsigned short*)kbuf, (unsigned short*)vbuf);
  down_kernel<<<NDOWN / 256, 256, 0, stream>>>(kbuf, vbuf, dwn_w, dwn_b, kdbuf, vdbuf);
  attn0_kernel<<<B * 32 * 32, 64, 0, stream>>>(qbuf, kbuf, vbuf, ybuf);
  attn1_kernel<<<B * 32 * 32, 64, 0, stream>>>(qbuf, kdbuf, vdbuf, ybuf);
  final_mfma_kernel<<<2048, 256, 0, stream>>>((const unsigned short*)ybuf,
                                              (const unsigned short*)x1buf, x0,
                                              sa_w, sa_b, po_w, po_b, out);
}

// Round 3
// 514.363 us; speedup vs baseline: 3.4987x; 2.0707x over previous
//
#include <hip/hip_runtime.h>
#include <hip/hip_bf16.h>

using bf16 = __hip_bfloat16;

constexpr int B = 8, C = 64, H = 256, W = 256;
constexpr int HWs = H * W;               // 65536
constexpr int NPIX = B * H * W;          // 524288
constexpr long long NELEM = (long long)B * C * H * W;  // 33554432
constexpr int CS = 32;
constexpr int Hd = 128, Wd = 128;
constexpr int HWd = Hd * Wd;             // 16384
constexpr int NDOWN = B * CS * HWd;      // 4194304
constexpr float EPS = 1e-6f;
constexpr float SCALE = 0.17677669529663687f;  // 32^-0.5

typedef __attribute__((ext_vector_type(8))) short short8v;
typedef __attribute__((ext_vector_type(8))) unsigned short ushort8v;
typedef __attribute__((ext_vector_type(4))) unsigned short ushort4v;
typedef __attribute__((ext_vector_type(4))) float f32x4;

__device__ __forceinline__ float b2f(bf16 v) { return __bfloat162float(v); }
__device__ __forceinline__ bf16 f2b(float v) { return __float2bfloat16(v); }
__device__ __forceinline__ unsigned short f2bu(float v) {
  bf16 t = __float2bfloat16(v);
  unsigned short u;
  __builtin_memcpy(&u, &t, 2);
  return u;
}
__device__ __forceinline__ float bu2f(unsigned short u) {
  bf16 t;
  __builtin_memcpy(&t, &u, 2);
  return __bfloat162float(t);
}

// ---- K1: channel LayerNorm over C (biased var), x0 f32 -> x bf16 ----
__global__ __launch_bounds__(256) void ln_kernel(
    const float* __restrict__ x0, const float* __restrict__ lw,
    const float* __restrict__ lb, bf16* __restrict__ xo) {
  int p = blockIdx.x * 256 + threadIdx.x;
  int b = p >> 16, hw = p & (HWs - 1);
  const float* xp = x0 + (size_t)b * C * HWs + hw;
  float xv[C];
  float s = 0.f;
#pragma unroll
  for (int c = 0; c < C; ++c) { xv[c] = xp[(size_t)c * HWs]; s += xv[c]; }
  float mu = s * (1.f / C);
  float vs = 0.f;
#pragma unroll
  for (int c = 0; c < C; ++c) { float d = xv[c] - mu; vs += d * d; }
  float rstd = rsqrtf(vs * (1.f / C) + EPS);
  bf16* yp = xo + (size_t)b * C * HWs + hw;
#pragma unroll
  for (int c = 0; c < C; ++c)
    yp[(size_t)c * HWs] = f2b(lw[c] * ((xv[c] - mu) * rstd) + lb[c]);
}

// ---- K2 v2: depthwise 3x3 + bias, 16 px/thread, vectorized rows ----
__global__ __launch_bounds__(256) void dw_kernel(
    const unsigned short* __restrict__ x, const float* __restrict__ dww,
    const float* __restrict__ dwb, unsigned short* __restrict__ x1,
    float* __restrict__ pool) {
  int tid = threadIdx.x;
  int tx = tid & 15, ty = tid >> 4;
  int h = blockIdx.x * 16 + ty;
  int c = blockIdx.y, b = blockIdx.z;
  const unsigned short* xp = x + ((size_t)b * C + c) * HWs;
  float kk[9];
#pragma unroll
  for (int i = 0; i < 9; ++i) kk[i] = dww[c * 9 + i];
  int w0 = tx * 16;
  float acc[16];
  float bias = dwb[c];
#pragma unroll
  for (int i = 0; i < 16; ++i) acc[i] = bias;
#pragma unroll
  for (int dr = 0; dr < 3; ++dr) {
    int hh = h + dr - 1;
    if (hh < 0 || hh >= H) continue;
    const unsigned short* rp = xp + hh * W;
    ushort8v r0 = *(const ushort8v*)(rp + w0);
    ushort8v r1 = *(const ushort8v*)(rp + w0 + 8);
    float p[18];
    p[0] = (w0 > 0) ? bu2f(rp[w0 - 1]) : 0.f;
    p[17] = (w0 + 16 < W) ? bu2f(rp[w0 + 16]) : 0.f;
#pragma unroll
    for (int i = 0; i < 8; ++i) { p[1 + i] = bu2f(r0[i]); p[9 + i] = bu2f(r1[i]); }
    float k0 = kk[dr * 3], k1 = kk[dr * 3 + 1], k2 = kk[dr * 3 + 2];
#pragma unroll
    for (int i = 0; i < 16; ++i)
      acc[i] += k0 * p[i] + k1 * p[i + 1] + k2 * p[i + 2];
  }
  ushort8v o0, o1;
  float s = 0.f;
#pragma unroll
  for (int i = 0; i < 8; ++i) { o0[i] = f2bu(acc[i]); o1[i] = f2bu(acc[i + 8]); }
#pragma unroll
  for (int i = 0; i < 16; ++i) s += acc[i];
  size_t ob = ((size_t)b * C + c) * HWs + h * W + w0;
  *(ushort8v*)(x1 + ob) = o0;
  *(ushort8v*)(x1 + ob + 8) = o1;
#pragma unroll
  for (int off = 32; off > 0; off >>= 1) s += __shfl_down(s, off, 64);
  __shared__ float red[4];
  if ((tid & 63) == 0) red[tid >> 6] = s;
  __syncthreads();
  if (tid == 0) atomicAdd(&pool[b * C + c], red[0] + red[1] + red[2] + red[3]);
}

// ---- K3: ECA channel attention from pooled means -> ca[b][c] (sigmoid) ----
__global__ __launch_bounds__(512) void eca_kernel(
    const float* __restrict__ pool, const float* __restrict__ w1,
    const float* __restrict__ w2, const float* __restrict__ w3,
    const float* __restrict__ wc, float* __restrict__ ca) {
  int tid = threadIdx.x;          // 0..511
  int b = tid >> 6, c = tid & 63;
  __shared__ float m[8][64], t1[8][64], t2[8][64], t3[8][64];
  m[b][c] = pool[tid] * (1.f / HWs);
  __syncthreads();
  auto gm = [&](int cc) -> float { return (cc >= 0 && cc < 64) ? m[b][cc] : 0.f; };
  t1[b][c] = w1[0] * gm(c - 1) + w1[1] * gm(c) + w1[2] * gm(c + 1);
  t2[b][c] = w2[0] * gm(c - 2) + w2[1] * gm(c) + w2[2] * gm(c + 2);
  t3[b][c] = w3[0] * gm(c - 4) + w3[1] * gm(c) + w3[2] * gm(c + 4);
  __syncthreads();
  auto g1 = [&](int cc) -> float { return (cc >= 0 && cc < 64) ? t1[b][cc] : 0.f; };
  auto g2 = [&](int cc) -> float { return (cc >= 0 && cc < 64) ? t2[b][cc] : 0.f; };
  auto g3 = [&](int cc) -> float { return (cc >= 0 && cc < 64) ? t3[b][cc] : 0.f; };
  float z = 0.f;
#pragma unroll
  for (int k = 0; k < 3; ++k) {
    z += wc[0 * 3 + k] * g1(c + k - 1);
    z += wc[1 * 3 + k] * g2(c + k - 1);
    z += wc[2 * 3 + k] * g3(c + k - 1);
  }
  ca[tid] = 1.f / (1.f + __expf(-z));
}

// ---- K4 v2: q/k/v projections via MFMA; window-major stores.
// q0/k0/v0: ch 0..31 rolled(-4) window layout [b*1024+win][64 tok][32 ch].
// q1: ch 32..63 same window layout. ksp/vsp: ch 32..63 spatial (for down). ----
__global__ __launch_bounds__(256) void qkv_mfma_kernel(
    const unsigned short* __restrict__ x, const float* __restrict__ wq,
    const float* __restrict__ wk, const float* __restrict__ wv,
    const float* __restrict__ ca, unsigned short* __restrict__ q0,
    unsigned short* __restrict__ q1, unsigned short* __restrict__ k0,
    unsigned short* __restrict__ v0, unsigned short* __restrict__ ksp,
    unsigned short* __restrict__ vsp) {
  int lane = threadIdx.x & 63, wid = threadIdx.x >> 6;
  int lr = lane & 15, lg = lane >> 4;
  short8v aq[4][2], ak[4][2], av[4][2];
#pragma unroll
  for (int mt = 0; mt < 4; ++mt)
#pragma unroll
    for (int ks = 0; ks < 2; ++ks) {
      int rowoff = (mt * 16 + lr) * 64 + ks * 32 + lg * 4;
      short8v tq, tk, tv;
#pragma unroll
      for (int j = 0; j < 8; ++j) {
        int kj = (j & 3) + 16 * (j >> 2);
        tq[j] = (short)f2bu(wq[rowoff + kj]);
        tk[j] = (short)f2bu(wk[rowoff + kj]);
        tv[j] = (short)f2bu(wv[rowoff + kj]);
      }
      aq[mt][ks] = tq; ak[mt][ks] = tk; av[mt][ks] = tv;
    }
  const int NT = NPIX / 16;
  for (int t = blockIdx.x * 4 + wid; t < NT; t += gridDim.x * 4) {
    int p0 = t * 16;
    int b = p0 >> 16;
    int hw0 = p0 & (HWs - 1);
    const unsigned short* xp = x + (size_t)b * C * HWs + hw0 + lr;
    short8v bx[2];
#pragma unroll
    for (int ks = 0; ks < 2; ++ks) {
      short8v tt;
#pragma unroll
      for (int j = 0; j < 8; ++j) {
        int c = ks * 32 + lg * 4 + (j & 3) + 16 * (j >> 2);
        tt[j] = (short)xp[(size_t)c * HWs];
      }
      bx[ks] = tt;
    }
    f32x4 zero = {0.f, 0.f, 0.f, 0.f};
    f32x4 acq[4], ack[4], acv[4];
#pragma unroll
    for (int mt = 0; mt < 4; ++mt) {
      acq[mt] = __builtin_amdgcn_mfma_f32_16x16x32_bf16(aq[mt][0], bx[0], zero, 0, 0, 0);
      acq[mt] = __builtin_amdgcn_mfma_f32_16x16x32_bf16(aq[mt][1], bx[1], acq[mt], 0, 0, 0);
      ack[mt] = __builtin_amdgcn_mfma_f32_16x16x32_bf16(ak[mt][0], bx[0], zero, 0, 0, 0);
      ack[mt] = __builtin_amdgcn_mfma_f32_16x16x32_bf16(ak[mt][1], bx[1], ack[mt], 0, 0, 0);
      acv[mt] = __builtin_amdgcn_mfma_f32_16x16x32_bf16(av[mt][0], bx[0], zero, 0, 0, 0);
      acv[mt] = __builtin_amdgcn_mfma_f32_16x16x32_bf16(av[mt][1], bx[1], acv[mt], 0, 0, 0);
    }
    // window-rolled address (roll -4 both axes)
    int r = hw0 >> 8;
    int cpix = (hw0 & 255) + lr;
    int rr = (r - 4) & 255, cc = (cpix - 4) & 255;
    int windex = b * 1024 + (rr >> 3) * 32 + (cc >> 3);
    int tok = (rr & 7) * 8 + (cc & 7);
    size_t wbase = (size_t)windex * 2048 + (size_t)tok * 32;
    const float* cab = ca + b * 64;
#pragma unroll
    for (int mt = 0; mt < 4; ++mt) {
      int och = mt * 16 + lg * 4;
      ushort4v hq, hk, hv;
#pragma unroll
      for (int i = 0; i < 4; ++i) {
        hq[i] = f2bu(acq[mt][i]);
        hk[i] = f2bu(ack[mt][i]);
        hv[i] = f2bu(acv[mt][i] * cab[och + i]);
      }
      if (mt < 2) {
        *(ushort4v*)(q0 + wbase + och) = hq;
        *(ushort4v*)(k0 + wbase + och) = hk;
        *(ushort4v*)(v0 + wbase + och) = hv;
      } else {
        *(ushort4v*)(q1 + wbase + (och - 32)) = hq;
        size_t sb = ((size_t)b * 32 + (och - 32)) * HWs + hw0 + lr;
#pragma unroll
        for (int i = 0; i < 4; ++i) {
          ksp[sb + (size_t)i * HWs] = hk[i];
          vsp[sb + (size_t)i * HWs] = hv[i];
        }
      }
    }
  }
}

// ---- K5 v2: 2x2 stride-2 downsample of ksp/vsp -> rolled(-2) window layout
// kdw/vdw: [b*1024+win][32 ch][16 tok] ----
__global__ __launch_bounds__(256) void down_kernel(
    const unsigned short* __restrict__ ksp, const unsigned short* __restrict__ vsp,
    const float* __restrict__ dw, const float* __restrict__ db,
    unsigned short* __restrict__ kdw, unsigned short* __restrict__ vdw) {
  int t = blockIdx.x * 256 + threadIdx.x;   // < B*CS*Hd*32 = 1048576
  int wxd = t & 31, i = (t >> 5) & 127, c = (t >> 12) & 31, b = t >> 17;
  const unsigned short* kp = ksp + ((size_t)b * 32 + c) * HWs;
  const unsigned short* vp = vsp + ((size_t)b * 32 + c) * HWs;
  float w00 = dw[c * 4], w01 = dw[c * 4 + 1], w10 = dw[c * 4 + 2], w11 = dw[c * 4 + 3];
  float bias = db[c];
  int rowa = (2 * i) * W, rowb = rowa + W;
  int rr = (i - 2) & 127;
  size_t sb = ((size_t)(b * 1024 + (rr >> 2) * 32 + wxd)) * 512 + (size_t)c * 16 + (rr & 3) * 4;
  ushort4v hk, hv;
#pragma unroll
  for (int tx = 0; tx < 4; ++tx) {
    int j = (wxd * 4 + tx + 2) & 127;
    int c0 = 2 * j;
    float ka = w00 * bu2f(kp[rowa + c0]) + w01 * bu2f(kp[rowa + c0 + 1]) +
               w10 * bu2f(kp[rowb + c0]) + w11 * bu2f(kp[rowb + c0 + 1]) + bias;
    float va = w00 * bu2f(vp[rowa + c0]) + w01 * bu2f(vp[rowa + c0 + 1]) +
               w10 * bu2f(vp[rowb + c0]) + w11 * bu2f(vp[rowb + c0 + 1]) + bias;
    hk[tx] = f2bu(ka);
    hv[tx] = f2bu(va);
  }
  *(ushort4v*)(kdw + sb) = hk;
  *(ushort4v*)(vdw + sb) = hv;
}

// ---- K6 v2: branch 0 window attention; contiguous window-major loads ----
__global__ __launch_bounds__(64) void attn0_kernel(
    const unsigned short* __restrict__ q0, const unsigned short* __restrict__ k0,
    const unsigned short* __restrict__ v0, bf16* __restrict__ y) {
  __shared__ float ks_[64][33];
  __shared__ float vs_[64][33];
  int widx = blockIdx.x;
  int b = widx >> 10, wy = (widx >> 5) & 31, wx = widx & 31;
  int t = threadIdx.x;
  size_t wbase = (size_t)widx * 2048 + (size_t)t * 32;
  float qv[32];
#pragma unroll
  for (int j = 0; j < 4; ++j) {
    ushort8v qa = *(const ushort8v*)(q0 + wbase + j * 8);
    ushort8v ka = *(const ushort8v*)(k0 + wbase + j * 8);
    ushort8v va = *(const ushort8v*)(v0 + wbase + j * 8);
#pragma unroll
    for (int i = 0; i < 8; ++i) {
      qv[j * 8 + i] = bu2f(qa[i]);
      ks_[t][j * 8 + i] = bu2f(ka[i]);
      vs_[t][j * 8 + i] = bu2f(va[i]);
    }
  }
  __syncthreads();
  float s[64];
  float mx = -1e30f;
#pragma unroll
  for (int j = 0; j < 64; ++j) {
    float acc = 0.f;
#pragma unroll
    for (int c = 0; c < 32; ++c) acc += qv[c] * ks_[j][c];
    acc *= SCALE;
    s[j] = acc;
    mx = fmaxf(mx, acc);
  }
  float sum = 0.f;
#pragma unroll
  for (int j = 0; j < 64; ++j) { s[j] = __expf(s[j] - mx); sum += s[j]; }
  float inv = 1.f / sum;
  float yv[32];
#pragma unroll
  for (int c = 0; c < 32; ++c) yv[c] = 0.f;
#pragma unroll
  for (int j = 0; j < 64; ++j) {
    float pj = s[j] * inv;
#pragma unroll
    for (int c = 0; c < 32; ++c) yv[c] += pj * vs_[j][c];
  }
  int ty = t >> 3, tx = t & 7;
  int r = (wy * 8 + ty + 4) & 255, cc = (wx * 8 + tx + 4) & 255;
  size_t base = (size_t)b * C * HWs + r * W + cc;
#pragma unroll
  for (int c = 0; c < 32; ++c) y[base + (size_t)c * HWs] = f2b(yv[c]);
}

// ---- K7 v2: branch 1; q window-major, k/v downsampled window-major ----
__global__ __launch_bounds__(64) void attn1_kernel(
    const unsigned short* __restrict__ q1, const unsigned short* __restrict__ kd,
    const unsigned short* __restrict__ vd, bf16* __restrict__ y) {
  __shared__ float ks_[16][33];
  __shared__ float vs_[16][33];
  int widx = blockIdx.x;
  int b = widx >> 10, wy = (widx >> 5) & 31, wx = widx & 31;
  int t = threadIdx.x;
  {  // stage one 32ch x 16tok window: lane t covers ch=t>>1, toks (t&1)*8..+7
    size_t off = (size_t)widx * 512 + (size_t)t * 8;
    ushort8v kk8 = *(const ushort8v*)(kd + off);
    ushort8v vv8 = *(const ushort8v*)(vd + off);
    int ch = t >> 1, tok0 = (t & 1) * 8;
#pragma unroll
    for (int i = 0; i < 8; ++i) {
      ks_[tok0 + i][ch] = bu2f(kk8[i]);
      vs_[tok0 + i][ch] = bu2f(vv8[i]);
    }
  }
  size_t wbase = (size_t)widx * 2048 + (size_t)t * 32;
  float qv[32];
#pragma unroll
  for (int j = 0; j < 4; ++j) {
    ushort8v qa = *(const ushort8v*)(q1 + wbase + j * 8);
#pragma unroll
    for (int i = 0; i < 8; ++i) qv[j * 8 + i] = bu2f(qa[i]);
  }
  __syncthreads();
  float s[16];
  float mx = -1e30f;
#pragma unroll
  for (int j = 0; j < 16; ++j) {
    float acc = 0.f;
#pragma unroll
    for (int c = 0; c < 32; ++c) acc += qv[c] * ks_[j][c];
    acc *= SCALE;
    s[j] = acc;
    mx = fmaxf(mx, acc);
  }
  float sum = 0.f;
#pragma unroll
  for (int j = 0; j < 16; ++j) { s[j] = __expf(s[j] - mx); sum += s[j]; }
  float inv = 1.f / sum;
  float yv[32];
#pragma unroll
  for (int c = 0; c < 32; ++c) yv[c] = 0.f;
#pragma unroll
  for (int j = 0; j < 16; ++j) {
    float pj = s[j] * inv;
#pragma unroll
    for (int c = 0; c < 32; ++c) yv[c] += pj * vs_[j][c];
  }
  int ty = t >> 3, tx = t & 7;
  int r = (wy * 8 + ty + 4) & 255, cc = (wx * 8 + tx + 4) & 255;
  size_t base = ((size_t)b * C + 32) * HWs + r * W + cc;
#pragma unroll
  for (int c = 0; c < 32; ++c) y[base + (size_t)c * HWs] = f2b(yv[c]);
}

// ---- K8: fused spatial gate + output projection (MFMA) + residual ----
__global__ __launch_bounds__(256) void final_mfma_kernel(
    const unsigned short* __restrict__ y, const unsigned short* __restrict__ x1,
    const float* __restrict__ x0, const float* __restrict__ sa_w,
    const float* __restrict__ sa_b, const float* __restrict__ po_w,
    const float* __restrict__ po_b, float* __restrict__ out) {
  __shared__ unsigned short zs[64][72];
  __shared__ float part[4][64];
  __shared__ float sgs[64];
  int tid = threadIdx.x;
  int lane = tid & 63, wid = tid >> 6;
  int lr = lane & 15, lg = lane >> 4;
  short8v ap[4][2];
#pragma unroll
  for (int mt = 0; mt < 4; ++mt)
#pragma unroll
    for (int ks = 0; ks < 2; ++ks) {
      int rowoff = (mt * 16 + lr) * 64 + ks * 32 + lg * 4;
      short8v tt;
#pragma unroll
      for (int j = 0; j < 8; ++j) {
        int kj = (j & 3) + 16 * (j >> 2);
        tt[j] = (short)f2bu(po_w[rowoff + kj]);
      }
      ap[mt][ks] = tt;
    }
  int cc = tid >> 2, qx = (tid & 3) * 16;
  const int NBLK = NPIX / 64;
  for (int blk = blockIdx.x; blk < NBLK; blk += gridDim.x) {
    int p0 = blk * 64;
    int b = p0 >> 16, hw0 = p0 & (HWs - 1);
    size_t rbase = (size_t)b * C * HWs + (size_t)cc * HWs + hw0 + qx;
    ushort8v y0 = *(const ushort8v*)(y + rbase);
    ushort8v y1 = *(const ushort8v*)(y + rbase + 8);
    ushort8v a0 = *(const ushort8v*)(x1 + rbase);
    ushort8v a1 = *(const ushort8v*)(x1 + rbase + 8);
    *(ushort8v*)&zs[cc][qx] = y0;
    *(ushort8v*)&zs[cc][qx + 8] = y1;
    __syncthreads();
    {
      int p = tid & 63, qr = tid >> 6;
      float s = 0.f;
#pragma unroll
      for (int c2 = 0; c2 < 16; ++c2)
        s += sa_w[qr * 16 + c2] * bu2f(zs[qr * 16 + c2][p]);
      part[qr][p] = s;
    }
    __syncthreads();
    if (tid < 64) {
      float sd = part[0][tid] + part[1][tid] + part[2][tid] + part[3][tid] + sa_b[0];
      sgs[tid] = 1.f / (1.f + __expf(-sd));
    }
    __syncthreads();
    {
      ushort8v z0, z1;
#pragma unroll
      for (int i = 0; i < 8; ++i) {
        z0[i] = f2bu(bu2f(y0[i]) + sgs[qx + i] * bu2f(a0[i]));
        z1[i] = f2bu(bu2f(y1[i]) + sgs[qx + 8 + i] * bu2f(a1[i]));
      }
      *(ushort8v*)&zs[cc][qx] = z0;
      *(ushort8v*)&zs[cc][qx + 8] = z1;
    }
    __syncthreads();
    short8v bz[2];
#pragma unroll
    for (int ks = 0; ks < 2; ++ks) {
      short8v tt;
#pragma unroll
      for (int j = 0; j < 8; ++j) {
        int c2 = ks * 32 + lg * 4 + (j & 3) + 16 * (j >> 2);
        tt[j] = (short)zs[c2][wid * 16 + lr];
      }
      bz[ks] = tt;
    }
    f32x4 zero = {0.f, 0.f, 0.f, 0.f};
    f32x4 acc[4];
#pragma unroll
    for (int mt = 0; mt < 4; ++mt) {
      acc[mt] = __builtin_amdgcn_mfma_f32_16x16x32_bf16(ap[mt][0], bz[0], zero, 0, 0, 0);
      acc[mt] = __builtin_amdgcn_mfma_f32_16x16x32_bf16(ap[mt][1], bz[1], acc[mt], 0, 0, 0);
    }
    size_t pbase = (size_t)b * C * HWs + hw0 + wid * 16 + lr;
#pragma unroll
    for (int mt = 0; mt < 4; ++mt)
#pragma unroll
      for (int i = 0; i < 4; ++i) {
        int o = mt * 16 + lg * 4 + i;
        out[pbase + (size_t)o * HWs] = acc[mt][i] + po_b[o] + x0[pbase + (size_t)o * HWs];
      }
    __syncthreads();
  }
}

extern "C" void kernel_launch(void* const* d_in, const int* in_sizes, int n_in,
                              void* d_out, int out_size, void* d_ws, size_t ws_size,
                              hipStream_t stream) {
  const float* x0    = (const float*)d_in[0];
  const float* ln_w  = (const float*)d_in[1];
  const float* ln_b  = (const float*)d_in[2];
  const float* dw_w  = (const float*)d_in[3];
  const float* dw_b  = (const float*)d_in[4];
  const float* ew1   = (const float*)d_in[5];
  const float* ew2   = (const float*)d_in[6];
  const float* ew3   = (const float*)d_in[7];
  const float* ewc   = (const float*)d_in[8];
  const float* wq    = (const float*)d_in[9];
  const float* wk    = (const float*)d_in[10];
  const float* wv    = (const float*)d_in[11];
  const float* dwn_w = (const float*)d_in[12];
  const float* dwn_b = (const float*)d_in[13];
  const float* sa_w  = (const float*)d_in[14];
  const float* sa_b  = (const float*)d_in[15];
  const float* po_w  = (const float*)d_in[16];
  const float* po_b  = (const float*)d_in[17];
  float* out = (float*)d_out;

  char* ws = (char*)d_ws;
  const size_t NB = (size_t)NELEM * sizeof(bf16);     // 67,108,864
  const size_t NH = NB / 2;                            // 33,554,432
  const size_t NDB = (size_t)NDOWN * sizeof(bf16);    // 8,388,608
  bf16* xbuf  = (bf16*)(ws);
  bf16* x1buf = (bf16*)(ws + NB);
  unsigned short* q0b  = (unsigned short*)(ws + 2 * NB);
  unsigned short* q1b  = (unsigned short*)(ws + 2 * NB + NH);
  unsigned short* k0b  = (unsigned short*)(ws + 3 * NB);
  unsigned short* v0b  = (unsigned short*)(ws + 3 * NB + NH);
  unsigned short* kspb = (unsigned short*)(ws + 4 * NB);
  unsigned short* vspb = (unsigned short*)(ws + 4 * NB + NH);
  unsigned short* kdwb = (unsigned short*)(ws + 5 * NB);
  unsigned short* vdwb = (unsigned short*)(ws + 5 * NB + NDB);
  float* pool = (float*)(ws + 5 * NB + 2 * NDB);
  float* cabuf = pool + B * C;
  bf16* ybuf = xbuf;  // x dead after qkv; reuse for attention output

  hipMemsetAsync(pool, 0, B * C * sizeof(float), stream);
  ln_kernel<<<NPIX / 256, 256, 0, stream>>>(x0, ln_w, ln_b, xbuf);
  dw_kernel<<<dim3(16, C, B), 256, 0, stream>>>((const unsigned short*)xbuf, dw_w, dw_b,
                                                (unsigned short*)x1buf, pool);
  eca_kernel<<<1, 512, 0, stream>>>(pool, ew1, ew2, ew3, ewc, cabuf);
  qkv_mfma_kernel<<<2048, 256, 0, stream>>>((const unsigned short*)xbuf, wq, wk, wv,
                                            cabuf, q0b, q1b, k0b, v0b, kspb, vspb);
  down_kernel<<<4096, 256, 0, stream>>>(kspb, vspb, dwn_w, dwn_b, kdwb, vdwb);
  attn0_kernel<<<B * 1024, 64, 0, stream>>>(q0b, k0b, v0b, ybuf);
  attn1_kernel<<<B * 1024, 64, 0, stream>>>(q1b, kdwb, vdwb, ybuf);
  final_mfma_kernel<<<2048, 256, 0, stream>>>((const unsigned short*)ybuf,
                                              (const unsigned short*)x1buf, x0,
                                              sa_w, sa_b, po_w, po_b, out);
}

// Round 4
// 401.940 us; speedup vs baseline: 4.4773x; 1.2797x over previous
//
#include <hip/hip_runtime.h>
#include <hip/hip_bf16.h>

using bf16 = __hip_bfloat16;

constexpr int B = 8, C = 64, H = 256, W = 256;
constexpr int HWs = H * W;               // 65536
constexpr int NPIX = B * H * W;          // 524288
constexpr long long NELEM = (long long)B * C * H * W;  // 33554432
constexpr int CS = 32;
constexpr int Hd = 128, Wd = 128;
constexpr int HWd = Hd * Wd;             // 16384
constexpr int NDOWN = B * CS * HWd;      // 4194304
constexpr float EPS = 1e-6f;
constexpr float SCALE = 0.17677669529663687f;  // 32^-0.5

typedef __attribute__((ext_vector_type(8))) short short8v;
typedef __attribute__((ext_vector_type(8))) unsigned short ushort8v;
typedef __attribute__((ext_vector_type(4))) unsigned short ushort4v;
typedef __attribute__((ext_vector_type(4))) float f32x4;

__device__ __forceinline__ float b2f(bf16 v) { return __bfloat162float(v); }
__device__ __forceinline__ bf16 f2b(float v) { return __float2bfloat16(v); }
__device__ __forceinline__ unsigned short f2bu(float v) {
  bf16 t = __float2bfloat16(v);
  unsigned short u;
  __builtin_memcpy(&u, &t, 2);
  return u;
}
__device__ __forceinline__ float bu2f(unsigned short u) {
  bf16 t;
  __builtin_memcpy(&t, &u, 2);
  return __bfloat162float(t);
}
__device__ __forceinline__ short8v pack2(ushort4v a, ushort4v b) {
  short8v r;
  r[0] = (short)a[0]; r[1] = (short)a[1]; r[2] = (short)a[2]; r[3] = (short)a[3];
  r[4] = (short)b[0]; r[5] = (short)b[1]; r[6] = (short)b[2]; r[7] = (short)b[3];
  return r;
}

// ---- K1: channel LayerNorm over C (biased var), x0 f32 -> x bf16 ----
__global__ __launch_bounds__(256) void ln_kernel(
    const float* __restrict__ x0, const float* __restrict__ lw,
    const float* __restrict__ lb, bf16* __restrict__ xo) {
  int p = blockIdx.x * 256 + threadIdx.x;
  int b = p >> 16, hw = p & (HWs - 1);
  const float* xp = x0 + (size_t)b * C * HWs + hw;
  float xv[C];
  float s = 0.f;
#pragma unroll
  for (int c = 0; c < C; ++c) { xv[c] = xp[(size_t)c * HWs]; s += xv[c]; }
  float mu = s * (1.f / C);
  float vs = 0.f;
#pragma unroll
  for (int c = 0; c < C; ++c) { float d = xv[c] - mu; vs += d * d; }
  float rstd = rsqrtf(vs * (1.f / C) + EPS);
  bf16* yp = xo + (size_t)b * C * HWs + hw;
#pragma unroll
  for (int c = 0; c < C; ++c)
    yp[(size_t)c * HWs] = f2b(lw[c] * ((xv[c] - mu) * rstd) + lb[c]);
}

// ---- K2: depthwise 3x3 + bias, 16 px/thread, vectorized rows ----
__global__ __launch_bounds__(256) void dw_kernel(
    const unsigned short* __restrict__ x, const float* __restrict__ dww,
    const float* __restrict__ dwb, unsigned short* __restrict__ x1,
    float* __restrict__ pool) {
  int tid = threadIdx.x;
  int tx = tid & 15, ty = tid >> 4;
  int h = blockIdx.x * 16 + ty;
  int c = blockIdx.y, b = blockIdx.z;
  const unsigned short* xp = x + ((size_t)b * C + c) * HWs;
  float kk[9];
#pragma unroll
  for (int i = 0; i < 9; ++i) kk[i] = dww[c * 9 + i];
  int w0 = tx * 16;
  float acc[16];
  float bias = dwb[c];
#pragma unroll
  for (int i = 0; i < 16; ++i) acc[i] = bias;
#pragma unroll
  for (int dr = 0; dr < 3; ++dr) {
    int hh = h + dr - 1;
    if (hh < 0 || hh >= H) continue;
    const unsigned short* rp = xp + hh * W;
    ushort8v r0 = *(const ushort8v*)(rp + w0);
    ushort8v r1 = *(const ushort8v*)(rp + w0 + 8);
    float p[18];
    p[0] = (w0 > 0) ? bu2f(rp[w0 - 1]) : 0.f;
    p[17] = (w0 + 16 < W) ? bu2f(rp[w0 + 16]) : 0.f;
#pragma unroll
    for (int i = 0; i < 8; ++i) { p[1 + i] = bu2f(r0[i]); p[9 + i] = bu2f(r1[i]); }
    float k0 = kk[dr * 3], k1 = kk[dr * 3 + 1], k2 = kk[dr * 3 + 2];
#pragma unroll
    for (int i = 0; i < 16; ++i)
      acc[i] += k0 * p[i] + k1 * p[i + 1] + k2 * p[i + 2];
  }
  ushort8v o0, o1;
  float s = 0.f;
#pragma unroll
  for (int i = 0; i < 8; ++i) { o0[i] = f2bu(acc[i]); o1[i] = f2bu(acc[i + 8]); }
#pragma unroll
  for (int i = 0; i < 16; ++i) s += acc[i];
  size_t ob = ((size_t)b * C + c) * HWs + h * W + w0;
  *(ushort8v*)(x1 + ob) = o0;
  *(ushort8v*)(x1 + ob + 8) = o1;
#pragma unroll
  for (int off = 32; off > 0; off >>= 1) s += __shfl_down(s, off, 64);
  __shared__ float red[4];
  if ((tid & 63) == 0) red[tid >> 6] = s;
  __syncthreads();
  if (tid == 0) atomicAdd(&pool[b * C + c], red[0] + red[1] + red[2] + red[3]);
}

// ---- K3: ECA channel attention ----
__global__ __launch_bounds__(512) void eca_kernel(
    const float* __restrict__ pool, const float* __restrict__ w1,
    const float* __restrict__ w2, const float* __restrict__ w3,
    const float* __restrict__ wc, float* __restrict__ ca) {
  int tid = threadIdx.x;
  int b = tid >> 6, c = tid & 63;
  __shared__ float m[8][64], t1[8][64], t2[8][64], t3[8][64];
  m[b][c] = pool[tid] * (1.f / HWs);
  __syncthreads();
  auto gm = [&](int cc) -> float { return (cc >= 0 && cc < 64) ? m[b][cc] : 0.f; };
  t1[b][c] = w1[0] * gm(c - 1) + w1[1] * gm(c) + w1[2] * gm(c + 1);
  t2[b][c] = w2[0] * gm(c - 2) + w2[1] * gm(c) + w2[2] * gm(c + 2);
  t3[b][c] = w3[0] * gm(c - 4) + w3[1] * gm(c) + w3[2] * gm(c + 4);
  __syncthreads();
  auto g1 = [&](int cc) -> float { return (cc >= 0 && cc < 64) ? t1[b][cc] : 0.f; };
  auto g2 = [&](int cc) -> float { return (cc >= 0 && cc < 64) ? t2[b][cc] : 0.f; };
  auto g3 = [&](int cc) -> float { return (cc >= 0 && cc < 64) ? t3[b][cc] : 0.f; };
  float z = 0.f;
#pragma unroll
  for (int k = 0; k < 3; ++k) {
    z += wc[0 * 3 + k] * g1(c + k - 1);
    z += wc[1 * 3 + k] * g2(c + k - 1);
    z += wc[2 * 3 + k] * g3(c + k - 1);
  }
  ca[tid] = 1.f / (1.f + __expf(-z));
}

// ---- K4: q/k/v projections via MFMA; window-major stores ----
__global__ __launch_bounds__(256) void qkv_mfma_kernel(
    const unsigned short* __restrict__ x, const float* __restrict__ wq,
    const float* __restrict__ wk, const float* __restrict__ wv,
    const float* __restrict__ ca, unsigned short* __restrict__ q0,
    unsigned short* __restrict__ q1, unsigned short* __restrict__ k0,
    unsigned short* __restrict__ v0, unsigned short* __restrict__ ksp,
    unsigned short* __restrict__ vsp) {
  int lane = threadIdx.x & 63, wid = threadIdx.x >> 6;
  int lr = lane & 15, lg = lane >> 4;
  short8v aq[4][2], ak[4][2], av[4][2];
#pragma unroll
  for (int mt = 0; mt < 4; ++mt)
#pragma unroll
    for (int ks = 0; ks < 2; ++ks) {
      int rowoff = (mt * 16 + lr) * 64 + ks * 32 + lg * 4;
      short8v tq, tk, tv;
#pragma unroll
      for (int j = 0; j < 8; ++j) {
        int kj = (j & 3) + 16 * (j >> 2);
        tq[j] = (short)f2bu(wq[rowoff + kj]);
        tk[j] = (short)f2bu(wk[rowoff + kj]);
        tv[j] = (short)f2bu(wv[rowoff + kj]);
      }
      aq[mt][ks] = tq; ak[mt][ks] = tk; av[mt][ks] = tv;
    }
  const int NT = NPIX / 16;
  for (int t = blockIdx.x * 4 + wid; t < NT; t += gridDim.x * 4) {
    int p0 = t * 16;
    int b = p0 >> 16;
    int hw0 = p0 & (HWs - 1);
    const unsigned short* xp = x + (size_t)b * C * HWs + hw0 + lr;
    short8v bx[2];
#pragma unroll
    for (int ks = 0; ks < 2; ++ks) {
      short8v tt;
#pragma unroll
      for (int j = 0; j < 8; ++j) {
        int c = ks * 32 + lg * 4 + (j & 3) + 16 * (j >> 2);
        tt[j] = (short)xp[(size_t)c * HWs];
      }
      bx[ks] = tt;
    }
    f32x4 zero = {0.f, 0.f, 0.f, 0.f};
    f32x4 acq[4], ack[4], acv[4];
#pragma unroll
    for (int mt = 0; mt < 4; ++mt) {
      acq[mt] = __builtin_amdgcn_mfma_f32_16x16x32_bf16(aq[mt][0], bx[0], zero, 0, 0, 0);
      acq[mt] = __builtin_amdgcn_mfma_f32_16x16x32_bf16(aq[mt][1], bx[1], acq[mt], 0, 0, 0);
      ack[mt] = __builtin_amdgcn_mfma_f32_16x16x32_bf16(ak[mt][0], bx[0], zero, 0, 0, 0);
      ack[mt] = __builtin_amdgcn_mfma_f32_16x16x32_bf16(ak[mt][1], bx[1], ack[mt], 0, 0, 0);
      acv[mt] = __builtin_amdgcn_mfma_f32_16x16x32_bf16(av[mt][0], bx[0], zero, 0, 0, 0);
      acv[mt] = __builtin_amdgcn_mfma_f32_16x16x32_bf16(av[mt][1], bx[1], acv[mt], 0, 0, 0);
    }
    int r = hw0 >> 8;
    int cpix = (hw0 & 255) + lr;
    int rr = (r - 4) & 255, cc = (cpix - 4) & 255;
    int windex = b * 1024 + (rr >> 3) * 32 + (cc >> 3);
    int tok = (rr & 7) * 8 + (cc & 7);
    size_t wbase = (size_t)windex * 2048 + (size_t)tok * 32;
    const float* cab = ca + b * 64;
#pragma unroll
    for (int mt = 0; mt < 4; ++mt) {
      int och = mt * 16 + lg * 4;
      ushort4v hq, hk, hv;
#pragma unroll
      for (int i = 0; i < 4; ++i) {
        hq[i] = f2bu(acq[mt][i]);
        hk[i] = f2bu(ack[mt][i]);
        hv[i] = f2bu(acv[mt][i] * cab[och + i]);
      }
      if (mt < 2) {
        *(ushort4v*)(q0 + wbase + och) = hq;
        *(ushort4v*)(k0 + wbase + och) = hk;
        *(ushort4v*)(v0 + wbase + och) = hv;
      } else {
        *(ushort4v*)(q1 + wbase + (och - 32)) = hq;
        size_t sb = ((size_t)b * 32 + (och - 32)) * HWs + hw0 + lr;
#pragma unroll
        for (int i = 0; i < 4; ++i) {
          ksp[sb + (size_t)i * HWs] = hk[i];
          vsp[sb + (size_t)i * HWs] = hv[i];
        }
      }
    }
  }
}

// ---- K5: 2x2 stride-2 downsample; kdw -> [win][16tok][32ch], vdw -> [win][32ch][16tok] ----
__global__ __launch_bounds__(256) void down_kernel(
    const unsigned short* __restrict__ ksp, const unsigned short* __restrict__ vsp,
    const float* __restrict__ dw, const float* __restrict__ db,
    unsigned short* __restrict__ kdw, unsigned short* __restrict__ vdw) {
  int t = blockIdx.x * 256 + threadIdx.x;   // < 1048576
  int wxd = t & 31, i = (t >> 5) & 127, c = (t >> 12) & 31, b = t >> 17;
  const unsigned short* kp = ksp + ((size_t)b * 32 + c) * HWs;
  const unsigned short* vp = vsp + ((size_t)b * 32 + c) * HWs;
  float w00 = dw[c * 4], w01 = dw[c * 4 + 1], w10 = dw[c * 4 + 2], w11 = dw[c * 4 + 3];
  float bias = db[c];
  int rowa = (2 * i) * W, rowb = rowa + W;
  int rr = (i - 2) & 127;
  size_t winb = ((size_t)(b * 1024 + (rr >> 2) * 32 + wxd)) * 512;
  int tokrow = (rr & 3) * 4;
  ushort4v hk, hv;
#pragma unroll
  for (int tx = 0; tx < 4; ++tx) {
    int j = (wxd * 4 + tx + 2) & 127;
    int c0 = 2 * j;
    float ka = w00 * bu2f(kp[rowa + c0]) + w01 * bu2f(kp[rowa + c0 + 1]) +
               w10 * bu2f(kp[rowb + c0]) + w11 * bu2f(kp[rowb + c0 + 1]) + bias;
    float va = w00 * bu2f(vp[rowa + c0]) + w01 * bu2f(vp[rowa + c0 + 1]) +
               w10 * bu2f(vp[rowb + c0]) + w11 * bu2f(vp[rowb + c0 + 1]) + bias;
    hk[tx] = f2bu(ka);
    hv[tx] = f2bu(va);
  }
  *(ushort4v*)(vdw + winb + (size_t)c * 16 + tokrow) = hv;
#pragma unroll
  for (int tx = 0; tx < 4; ++tx)
    kdw[winb + (size_t)(tokrow + tx) * 32 + c] = hk[tx];
}

// ---- K6 v3: branch 0 window attention via MFMA.
// S^T = mfma(A=K, B=Q) per (kt,qt): lane holds P^T[k=lg*4+reg+16kt][q=lr].
// Softmax: in-lane over 16 regs + shfl_xor(16,32) across lg.
// PV: Y^T = mfma(A=V^T from LDS, B=P^T in-lane). Y^T -> LDS -> vector spatial store. ----
__global__ __launch_bounds__(256) void attn0_kernel(
    const unsigned short* __restrict__ q0, const unsigned short* __restrict__ k0,
    const unsigned short* __restrict__ v0, unsigned short* __restrict__ y) {
  __shared__ unsigned short zs[4][32][72];   // per-wave: V^T, then reused for Y^T
  int lane = threadIdx.x & 63, wid = threadIdx.x >> 6;
  int lr = lane & 15, lg = lane >> 4;
  int widx = blockIdx.x * 4 + wid;
  int b = widx >> 10, wy = (widx >> 5) & 31, wx = widx & 31;
  unsigned short* zw = &zs[wid][0][0];
  // stage V^T[32ch][64tok]: lane = tok, conflict-free writes
  {
    const unsigned short* vp = v0 + (size_t)widx * 2048 + (size_t)lane * 32;
#pragma unroll
    for (int j2 = 0; j2 < 4; ++j2) {
      ushort8v vv = *(const ushort8v*)(vp + j2 * 8);
#pragma unroll
      for (int i = 0; i < 8; ++i) zw[(j2 * 8 + i) * 72 + lane] = vv[i];
    }
  }
  // K and Q fragments from global (window-major, 8B loads)
  const unsigned short* kw = k0 + (size_t)widx * 2048;
  const unsigned short* qw = q0 + (size_t)widx * 2048;
  short8v kf[4], qf[4];
#pragma unroll
  for (int kt = 0; kt < 4; ++kt) {
    ushort4v a = *(const ushort4v*)(kw + (kt * 16 + lr) * 32 + lg * 4);
    ushort4v b2 = *(const ushort4v*)(kw + (kt * 16 + lr) * 32 + lg * 4 + 16);
    kf[kt] = pack2(a, b2);
  }
#pragma unroll
  for (int qt = 0; qt < 4; ++qt) {
    ushort4v a = *(const ushort4v*)(qw + (qt * 16 + lr) * 32 + lg * 4);
    ushort4v b2 = *(const ushort4v*)(qw + (qt * 16 + lr) * 32 + lg * 4 + 16);
    qf[qt] = pack2(a, b2);
  }
  __syncthreads();
  // V^T fragments (reused across qt); after this zs is reusable for Y
  short8v va[2][2];
#pragma unroll
  for (int mt = 0; mt < 2; ++mt)
#pragma unroll
    for (int ck = 0; ck < 2; ++ck) {
      ushort4v a = *(const ushort4v*)&zw[(mt * 16 + lr) * 72 + ck * 32 + lg * 4];
      ushort4v b2 = *(const ushort4v*)&zw[(mt * 16 + lr) * 72 + ck * 32 + lg * 4 + 16];
      va[mt][ck] = pack2(a, b2);
    }
  f32x4 zero = {0.f, 0.f, 0.f, 0.f};
#pragma unroll
  for (int qt = 0; qt < 4; ++qt) {
    f32x4 st[4];
#pragma unroll
    for (int kt = 0; kt < 4; ++kt)
      st[kt] = __builtin_amdgcn_mfma_f32_16x16x32_bf16(kf[kt], qf[qt], zero, 0, 0, 0);
    float mx = -1e30f;
#pragma unroll
    for (int kt = 0; kt < 4; ++kt)
#pragma unroll
      for (int r2 = 0; r2 < 4; ++r2) mx = fmaxf(mx, st[kt][r2]);
    mx = fmaxf(mx, __shfl_xor(mx, 16, 64));
    mx = fmaxf(mx, __shfl_xor(mx, 32, 64));
    float sum = 0.f;
#pragma unroll
    for (int kt = 0; kt < 4; ++kt)
#pragma unroll
      for (int r2 = 0; r2 < 4; ++r2) {
        float e = __expf(SCALE * (st[kt][r2] - mx));
        st[kt][r2] = e;
        sum += e;
      }
    sum += __shfl_xor(sum, 16, 64);
    sum += __shfl_xor(sum, 32, 64);
    float inv = 1.f / sum;
    short8v pb[2];
#pragma unroll
    for (int ck = 0; ck < 2; ++ck)
#pragma unroll
      for (int j = 0; j < 8; ++j)
        pb[ck][j] = (short)f2bu(st[ck * 2 + (j >> 2)][j & 3]);
#pragma unroll
    for (int mt = 0; mt < 2; ++mt) {
      f32x4 yt = __builtin_amdgcn_mfma_f32_16x16x32_bf16(va[mt][0], pb[0], zero, 0, 0, 0);
      yt = __builtin_amdgcn_mfma_f32_16x16x32_bf16(va[mt][1], pb[1], yt, 0, 0, 0);
#pragma unroll
      for (int r2 = 0; r2 < 4; ++r2)
        zw[(mt * 16 + lg * 4 + r2) * 72 + qt * 16 + lr] = f2bu(yt[r2] * inv);
    }
  }
  __syncthreads();
  // store Y^T -> spatial (rolled +4), two 8B vector stores per (ch,row)
  int ch = lane & 31, rh = lane >> 5;
  size_t ybase = ((size_t)b * C + ch) * HWs;
  int c1 = wx * 8 + 4, c2 = (wx * 8 + 8) & 255;
#pragma unroll
  for (int k2 = 0; k2 < 4; ++k2) {
    int row = rh * 4 + k2;
    ushort8v t8 = *(const ushort8v*)&zw[ch * 72 + row * 8];
    int r = (wy * 8 + row + 4) & 255;
    ushort4v lo, hi;
#pragma unroll
    for (int i = 0; i < 4; ++i) { lo[i] = t8[i]; hi[i] = t8[4 + i]; }
    *(ushort4v*)(y + ybase + r * W + c1) = lo;
    *(ushort4v*)(y + ybase + r * W + c2) = hi;
  }
}

// ---- K7 v3: branch 1 via MFMA (16 keys, zero-padded K slots) ----
__global__ __launch_bounds__(256) void attn1_kernel(
    const unsigned short* __restrict__ q1, const unsigned short* __restrict__ kdw,
    const unsigned short* __restrict__ vdw, unsigned short* __restrict__ y) {
  __shared__ unsigned short zs[4][32][72];
  int lane = threadIdx.x & 63, wid = threadIdx.x >> 6;
  int lr = lane & 15, lg = lane >> 4;
  int widx = blockIdx.x * 4 + wid;
  int b = widx >> 10, wy = (widx >> 5) & 31, wx = widx & 31;
  unsigned short* zw = &zs[wid][0][0];
  // K fragment: A=Kd [16tok][32ch]
  short8v kfr;
  {
    ushort4v a = *(const ushort4v*)(kdw + (size_t)widx * 512 + lr * 32 + lg * 4);
    ushort4v b2 = *(const ushort4v*)(kdw + (size_t)widx * 512 + lr * 32 + lg * 4 + 16);
    kfr = pack2(a, b2);
  }
  // V^T fragments: [32ch][16tok]; slots 4..7 zero (keys 16..31 absent)
  short8v va[2];
#pragma unroll
  for (int mt = 0; mt < 2; ++mt) {
    ushort4v a = *(const ushort4v*)(vdw + (size_t)widx * 512 + (mt * 16 + lr) * 16 + lg * 4);
    short8v t;
#pragma unroll
    for (int i = 0; i < 4; ++i) { t[i] = (short)a[i]; t[4 + i] = 0; }
    va[mt] = t;
  }
  const unsigned short* qw = q1 + (size_t)widx * 2048;
  short8v qf[4];
#pragma unroll
  for (int qt = 0; qt < 4; ++qt) {
    ushort4v a = *(const ushort4v*)(qw + (qt * 16 + lr) * 32 + lg * 4);
    ushort4v b2 = *(const ushort4v*)(qw + (qt * 16 + lr) * 32 + lg * 4 + 16);
    qf[qt] = pack2(a, b2);
  }
  f32x4 zero = {0.f, 0.f, 0.f, 0.f};
#pragma unroll
  for (int qt = 0; qt < 4; ++qt) {
    f32x4 st = __builtin_amdgcn_mfma_f32_16x16x32_bf16(kfr, qf[qt], zero, 0, 0, 0);
    float mx = fmaxf(fmaxf(st[0], st[1]), fmaxf(st[2], st[3]));
    mx = fmaxf(mx, __shfl_xor(mx, 16, 64));
    mx = fmaxf(mx, __shfl_xor(mx, 32, 64));
    float sum = 0.f;
#pragma unroll
    for (int r2 = 0; r2 < 4; ++r2) {
      float e = __expf(SCALE * (st[r2] - mx));
      st[r2] = e;
      sum += e;
    }
    sum += __shfl_xor(sum, 16, 64);
    sum += __shfl_xor(sum, 32, 64);
    float inv = 1.f / sum;
    short8v pb;
#pragma unroll
    for (int j = 0; j < 4; ++j) { pb[j] = (short)f2bu(st[j]); pb[4 + j] = 0; }
#pragma unroll
    for (int mt = 0; mt < 2; ++mt) {
      f32x4 yt = __builtin_amdgcn_mfma_f32_16x16x32_bf16(va[mt], pb, zero, 0, 0, 0);
#pragma unroll
      for (int r2 = 0; r2 < 4; ++r2)
        zw[(mt * 16 + lg * 4 + r2) * 72 + qt * 16 + lr] = f2bu(yt[r2] * inv);
    }
  }
  __syncthreads();
  int ch = lane & 31, rh = lane >> 5;
  size_t ybase = ((size_t)b * C + 32 + ch) * HWs;
  int c1 = wx * 8 + 4, c2 = (wx * 8 + 8) & 255;
#pragma unroll
  for (int k2 = 0; k2 < 4; ++k2) {
    int row = rh * 4 + k2;
    ushort8v t8 = *(const ushort8v*)&zw[ch * 72 + row * 8];
    int r = (wy * 8 + row + 4) & 255;
    ushort4v lo, hi;
#pragma unroll
    for (int i = 0; i < 4; ++i) { lo[i] = t8[i]; hi[i] = t8[4 + i]; }
    *(ushort4v*)(y + ybase + r * W + c1) = lo;
    *(ushort4v*)(y + ybase + r * W + c2) = hi;
  }
}

// ---- K8: fused spatial gate + output projection (MFMA) + residual ----
__global__ __launch_bounds__(256) void final_mfma_kernel(
    const unsigned short* __restrict__ y, const unsigned short* __restrict__ x1,
    const float* __restrict__ x0, const float* __restrict__ sa_w,
    const float* __restrict__ sa_b, const float* __restrict__ po_w,
    const float* __restrict__ po_b, float* __restrict__ out) {
  __shared__ unsigned short zs[64][72];
  __shared__ float part[4][64];
  __shared__ float sgs[64];
  int tid = threadIdx.x;
  int lane = tid & 63, wid = tid >> 6;
  int lr = lane & 15, lg = lane >> 4;
  short8v ap[4][2];
#pragma unroll
  for (int mt = 0; mt < 4; ++mt)
#pragma unroll
    for (int ks = 0; ks < 2; ++ks) {
      int rowoff = (mt * 16 + lr) * 64 + ks * 32 + lg * 4;
      short8v tt;
#pragma unroll
      for (int j = 0; j < 8; ++j) {
        int kj = (j & 3) + 16 * (j >> 2);
        tt[j] = (short)f2bu(po_w[rowoff + kj]);
      }
      ap[mt][ks] = tt;
    }
  int cc = tid >> 2, qx = (tid & 3) * 16;
  const int NBLK = NPIX / 64;
  for (int blk = blockIdx.x; blk < NBLK; blk += gridDim.x) {
    int p0 = blk * 64;
    int b = p0 >> 16, hw0 = p0 & (HWs - 1);
    size_t rbase = (size_t)b * C * HWs + (size_t)cc * HWs + hw0 + qx;
    ushort8v y0 = *(const ushort8v*)(y + rbase);
    ushort8v y1 = *(const ushort8v*)(y + rbase + 8);
    ushort8v a0 = *(const ushort8v*)(x1 + rbase);
    ushort8v a1 = *(const ushort8v*)(x1 + rbase + 8);
    *(ushort8v*)&zs[cc][qx] = y0;
    *(ushort8v*)&zs[cc][qx + 8] = y1;
    __syncthreads();
    {
      int p = tid & 63, qr = tid >> 6;
      float s = 0.f;
#pragma unroll
      for (int c2 = 0; c2 < 16; ++c2)
        s += sa_w[qr * 16 + c2] * bu2f(zs[qr * 16 + c2][p]);
      part[qr][p] = s;
    }
    __syncthreads();
    if (tid < 64) {
      float sd = part[0][tid] + part[1][tid] + part[2][tid] + part[3][tid] + sa_b[0];
      sgs[tid] = 1.f / (1.f + __expf(-sd));
    }
    __syncthreads();
    {
      ushort8v z0, z1;
#pragma unroll
      for (int i = 0; i < 8; ++i) {
        z0[i] = f2bu(bu2f(y0[i]) + sgs[qx + i] * bu2f(a0[i]));
        z1[i] = f2bu(bu2f(y1[i]) + sgs[qx + 8 + i] * bu2f(a1[i]));
      }
      *(ushort8v*)&zs[cc][qx] = z0;
      *(ushort8v*)&zs[cc][qx + 8] = z1;
    }
    __syncthreads();
    short8v bz[2];
#pragma unroll
    for (int ks = 0; ks < 2; ++ks) {
      short8v tt;
#pragma unroll
      for (int j = 0; j < 8; ++j) {
        int c2 = ks * 32 + lg * 4 + (j & 3) + 16 * (j >> 2);
        tt[j] = (short)zs[c2][wid * 16 + lr];
      }
      bz[ks] = tt;
    }
    f32x4 zero = {0.f, 0.f, 0.f, 0.f};
    f32x4 acc[4];
#pragma unroll
    for (int mt = 0; mt < 4; ++mt) {
      acc[mt] = __builtin_amdgcn_mfma_f32_16x16x32_bf16(ap[mt][0], bz[0], zero, 0, 0, 0);
      acc[mt] = __builtin_amdgcn_mfma_f32_16x16x32_bf16(ap[mt][1], bz[1], acc[mt], 0, 0, 0);
    }
    size_t pbase = (size_t)b * C * HWs + hw0 + wid * 16 + lr;
#pragma unroll
    for (int mt = 0; mt < 4; ++mt)
#pragma unroll
      for (int i = 0; i < 4; ++i) {
        int o = mt * 16 + lg * 4 + i;
        out[pbase + (size_t)o * HWs] = acc[mt][i] + po_b[o] + x0[pbase + (size_t)o * HWs];
      }
    __syncthreads();
  }
}

extern "C" void kernel_launch(void* const* d_in, const int* in_sizes, int n_in,
                              void* d_out, int out_size, void* d_ws, size_t ws_size,
                              hipStream_t stream) {
  const float* x0    = (const float*)d_in[0];
  const float* ln_w  = (const float*)d_in[1];
  const float* ln_b  = (const float*)d_in[2];
  const float* dw_w  = (const float*)d_in[3];
  const float* dw_b  = (const float*)d_in[4];
  const float* ew1   = (const float*)d_in[5];
  const float* ew2   = (const float*)d_in[6];
  const float* ew3   = (const float*)d_in[7];
  const float* ewc   = (const float*)d_in[8];
  const float* wq    = (const float*)d_in[9];
  const float* wk    = (const float*)d_in[10];
  const float* wv    = (const float*)d_in[11];
  const float* dwn_w = (const float*)d_in[12];
  const float* dwn_b = (const float*)d_in[13];
  const float* sa_w  = (const float*)d_in[14];
  const float* sa_b  = (const float*)d_in[15];
  const float* po_w  = (const float*)d_in[16];
  const float* po_b  = (const float*)d_in[17];
  float* out = (float*)d_out;

  char* ws = (char*)d_ws;
  const size_t NB = (size_t)NELEM * sizeof(bf16);
  const size_t NH = NB / 2;
  const size_t NDB = (size_t)NDOWN * sizeof(bf16);
  bf16* xbuf  = (bf16*)(ws);
  bf16* x1buf = (bf16*)(ws + NB);
  unsigned short* q0b  = (unsigned short*)(ws + 2 * NB);
  unsigned short* q1b  = (unsigned short*)(ws + 2 * NB + NH);
  unsigned short* k0b  = (unsigned short*)(ws + 3 * NB);
  unsigned short* v0b  = (unsigned short*)(ws + 3 * NB + NH);
  unsigned short* kspb = (unsigned short*)(ws + 4 * NB);
  unsigned short* vspb = (unsigned short*)(ws + 4 * NB + NH);
  unsigned short* kdwb = (unsigned short*)(ws + 5 * NB);
  unsigned short* vdwb = (unsigned short*)(ws + 5 * NB + NDB);
  float* pool = (float*)(ws + 5 * NB + 2 * NDB);
  float* cabuf = pool + B * C;
  bf16* ybuf = xbuf;  // x dead after qkv; reuse for attention output

  hipMemsetAsync(pool, 0, B * C * sizeof(float), stream);
  ln_kernel<<<NPIX / 256, 256, 0, stream>>>(x0, ln_w, ln_b, xbuf);
  dw_kernel<<<dim3(16, C, B), 256, 0, stream>>>((const unsigned short*)xbuf, dw_w, dw_b,
                                                (unsigned short*)x1buf, pool);
  eca_kernel<<<1, 512, 0, stream>>>(pool, ew1, ew2, ew3, ewc, cabuf);
  qkv_mfma_kernel<<<2048, 256, 0, stream>>>((const unsigned short*)xbuf, wq, wk, wv,
                                            cabuf, q0b, q1b, k0b, v0b, kspb, vspb);
  down_kernel<<<4096, 256, 0, stream>>>(kspb, vspb, dwn_w, dwn_b, kdwb, vdwb);
  attn0_kernel<<<2048, 256, 0, stream>>>(q0b, k0b, v0b, (unsigned short*)ybuf);
  attn1_kernel<<<2048, 256, 0, stream>>>(q1b, kdwb, vdwb, (unsigned short*)ybuf);
  final_mfma_kernel<<<2048, 256, 0, stream>>>((const unsigned short*)ybuf,
                                              (const unsigned short*)x1buf, x0,
                                              sa_w, sa_b, po_w, po_b, out);
}